// Round 10
// baseline (695.655 us; speedup 1.0000x reference)
//
#include <hip/hip_runtime.h>
#include <cstdint>

typedef __bf16 bf16x8 __attribute__((ext_vector_type(8)));
typedef float f32x4 __attribute__((ext_vector_type(4)));
typedef float f32x16 __attribute__((ext_vector_type(16)));
typedef short s16x4 __attribute__((ext_vector_type(4)));
typedef int i32x4 __attribute__((ext_vector_type(4)));

static __device__ __forceinline__ short bf_bits(float f) {
  uint32_t u = __builtin_bit_cast(uint32_t, f);
  u += 0x7fffu + ((u >> 16) & 1u);
  return (short)(u >> 16);
}
static __device__ __forceinline__ float bf_f(short s) {
  uint32_t u = ((uint32_t)(uint16_t)s) << 16;
  return __builtin_bit_cast(float, u);
}
static __device__ __forceinline__ bf16x8 ld_frag(const short* p) {
  i32x4 v = *reinterpret_cast<const i32x4*>(p);
  return __builtin_bit_cast(bf16x8, v);
}

typedef __attribute__((address_space(3))) uint32_t lds_u32_t;
typedef const __attribute__((address_space(1))) uint32_t glb_u32_t;
static __device__ __forceinline__ void gl_lds16(const void* g, const void* l) {
  __builtin_amdgcn_global_load_lds((glb_u32_t*)g,
                                   (lds_u32_t*)(uint32_t)(uintptr_t)l,
                                   16, 0, 0);
}

// ---------------- f32 -> bf16 convert ----------------
__global__ void cvt_bf16(const float* __restrict__ in, short* __restrict__ out, int n4) {
  int i = blockIdx.x * blockDim.x + threadIdx.x;
  if (i >= n4) return;
  float4 v = reinterpret_cast<const float4*>(in)[i];
  s16x4 o = { bf_bits(v.x), bf_bits(v.y), bf_bits(v.z), bf_bits(v.w) };
  reinterpret_cast<s16x4*>(out)[i] = o;
}

// ---------------- fused q/k/v weight convert into contiguous wb ----------------
__global__ void cvt_w(const float* __restrict__ qw, const float* __restrict__ kw,
                      const float* __restrict__ vw, short* __restrict__ out) {
  int i = blockIdx.x * blockDim.x + threadIdx.x;   // 1310720 float4s
  const float* src;
  int off;
  if (i < 1048576)      { src = qw; off = i; }
  else if (i < 1179648) { src = kw; off = i - 1048576; }
  else                  { src = vw; off = i - 1179648; }
  float4 v = reinterpret_cast<const float4*>(src)[off];
  s16x4 o = { bf_bits(v.x), bf_bits(v.y), bf_bits(v.z), bf_bits(v.w) };
  reinterpret_cast<s16x4*>(out)[i] = o;
}

// ---------------- RoPE tables: cos/sin [4096][128] f32 ----------------
__global__ void rope_table(float* __restrict__ ct, float* __restrict__ st) {
  int i = blockIdx.x * 256 + threadIdx.x;   // 524288
  int l = i >> 7, d = i & 127;
  float inv = expf(-0.07195578415625f * (float)d);   // ln(10000)/128
  float f = (float)l * inv;
  ct[i] = cosf(f);
  st[i] = sinf(f);
}

// ---------------- in-place RoPE on bf16 in fused qkv [8192][2560] ----------------
static __device__ __forceinline__ void rope_body(short* buf, const float* ct,
                                                 const float* st, int i, int cbase,
                                                 int hbits, float scale) {
  int dg = i & 31;
  int h = (i >> 5) & ((1 << hbits) - 1);
  int tok = i >> (5 + hbits);
  int l = tok & 4095;
  long base = (long)tok * 2560 + cbase + h * 256;
  int d = dg * 4;
  s16x4 x1 = *reinterpret_cast<const s16x4*>(buf + base + d);
  s16x4 x2 = *reinterpret_cast<const s16x4*>(buf + base + d + 128);
  float4 c = *reinterpret_cast<const float4*>(ct + l * 128 + d);
  float4 s = *reinterpret_cast<const float4*>(st + l * 128 + d);
  s16x4 o1, o2;
  o1.x = bf_bits((bf_f(x1.x) * c.x - bf_f(x2.x) * s.x) * scale);
  o1.y = bf_bits((bf_f(x1.y) * c.y - bf_f(x2.y) * s.y) * scale);
  o1.z = bf_bits((bf_f(x1.z) * c.z - bf_f(x2.z) * s.z) * scale);
  o1.w = bf_bits((bf_f(x1.w) * c.w - bf_f(x2.w) * s.w) * scale);
  o2.x = bf_bits((bf_f(x2.x) * c.x + bf_f(x1.x) * s.x) * scale);
  o2.y = bf_bits((bf_f(x2.y) * c.y + bf_f(x1.y) * s.y) * scale);
  o2.z = bf_bits((bf_f(x2.z) * c.z + bf_f(x1.z) * s.z) * scale);
  o2.w = bf_bits((bf_f(x2.w) * c.w + bf_f(x1.w) * s.w) * scale);
  *reinterpret_cast<s16x4*>(buf + base + d) = o1;
  *reinterpret_cast<s16x4*>(buf + base + d + 128) = o2;
}

// fused q-rope (i < 2097152, hbits=3, scale=1/16) + k-rope (hbits=0, col 2048)
__global__ void rope_fused(short* __restrict__ buf, const float* __restrict__ ct,
                           const float* __restrict__ st) {
  int j = blockIdx.x * blockDim.x + threadIdx.x;   // 2359296
  if (j < 2097152) rope_body(buf, ct, st, j, 0, 3, 0.0625f);
  else             rope_body(buf, ct, st, j - 2097152, 2048, 0, 1.0f);
}

// ---------------- V transpose: qkv cols 2304.. -> vt [2][256][4096] ----------------
__global__ void transpose_v(const short* __restrict__ qkv, short* __restrict__ vt) {
  int i = blockIdx.x * 256 + threadIdx.x;   // [b][lg 512][d 256], d fastest
  int d = i & 255;
  int lg = (i >> 8) & 511;
  int b = i >> 17;
  const short* src = qkv + ((long)b * 4096 + lg * 8) * 2560 + 2304 + d;
  short tmp[8];
  #pragma unroll
  for (int j = 0; j < 8; ++j) tmp[j] = src[(long)j * 2560];
  short* dst = vt + ((long)b * 256 + d) * 4096 + lg * 8;
  s16x4 lo = { tmp[0], tmp[1], tmp[2], tmp[3] };
  s16x4 hi4 = { tmp[4], tmp[5], tmp[6], tmp[7] };
  *reinterpret_cast<s16x4*>(dst) = lo;
  *reinterpret_cast<s16x4*>(dst + 4) = hi4;
}

// ---------------- GEMM: C[M,N] = A[M,K] @ B[N,K]^T, bf16, m97 structure ----------------
template <bool OUT_F32>
__global__ __launch_bounds__(256) void gemm_bt(const short* __restrict__ A,
                                               const short* __restrict__ B,
                                               void* __restrict__ C,
                                               int K, int ldc) {
  __shared__ short As[128 * 32];
  __shared__ short Bs[128 * 32];
  const int t = threadIdx.x;
  const int lane = t & 63;
  const int w = t >> 6;
  const long m0 = (long)blockIdx.x * 128;
  const long n0 = (long)blockIdx.y * 128;
  const int wr = (w >> 1) * 64, wc = (w & 1) * 64;
  const int fr = lane & 15, fk = (lane >> 4) * 8;
  f32x4 acc[4][4] = {};

  for (int k0 = 0; k0 < K; k0 += 32) {
    #pragma unroll
    for (int p = 0; p < 2; ++p) {
      int idx = p * 256 + t;
      gl_lds16(A + (m0 + (idx >> 2)) * K + k0 + (idx & 3) * 8, As + idx * 8);
    }
    #pragma unroll
    for (int p = 0; p < 2; ++p) {
      int idx = p * 256 + t;
      gl_lds16(B + (n0 + (idx >> 2)) * K + k0 + (idx & 3) * 8, Bs + idx * 8);
    }
    __syncthreads();
    bf16x8 af[4], bfr[4];
    #pragma unroll
    for (int i = 0; i < 4; ++i) af[i] = ld_frag(As + (wr + i * 16 + fr) * 32 + fk);
    #pragma unroll
    for (int j = 0; j < 4; ++j) bfr[j] = ld_frag(Bs + (wc + j * 16 + fr) * 32 + fk);
    #pragma unroll
    for (int i = 0; i < 4; ++i)
      #pragma unroll
      for (int j = 0; j < 4; ++j)
        acc[i][j] = __builtin_amdgcn_mfma_f32_16x16x32_bf16(af[i], bfr[j], acc[i][j], 0, 0, 0);
    __syncthreads();
  }
  const int er = lane >> 4, ec = lane & 15;
  #pragma unroll
  for (int i = 0; i < 4; ++i)
    #pragma unroll
    for (int j = 0; j < 4; ++j) {
      long col = n0 + wc + j * 16 + ec;
      #pragma unroll
      for (int r = 0; r < 4; ++r) {
        long row = m0 + wr + i * 16 + er * 4 + r;
        if constexpr (OUT_F32)
          reinterpret_cast<float*>(C)[row * ldc + col] = acc[i][j][r];
        else
          reinterpret_cast<short*>(C)[row * ldc + col] = bf_bits(acc[i][j][r]);
      }
    }
}

// ---------------- Flash attention (r2 structure; ONLY change: QK^T S0/S1 split) ----------------
// qkv [8192][2560] bf16 (q pre-scaled by 1/16, roped; k roped at col 2048)
// vt  [2][256][4096] bf16 ;  out -> og [8192][2048] bf16
__global__ __launch_bounds__(256, 2) void attn(const short* __restrict__ qkv,
                                               const short* __restrict__ vtg,
                                               short* __restrict__ og) {
  __shared__ __align__(16) short KtS[2 * 32 * 256];   // 2 x 16KB, XOR-swizzled 512B rows
  __shared__ __align__(16) short VtS[2 * 256 * 32];   // 2 x 16KB, XOR-swizzled 64B rows
  const int t = threadIdx.x;
  const int lane = t & 63, w = t >> 6;
  const int lq = lane & 31, hi = lane >> 5;
  // XCD swizzle: batch b -> XCD half so each XCD's 4MB L2 holds one batch's K+V^T
  const int u = blockIdx.x;
  const int b = (u >> 2) & 1;
  const int local = (u & 3) | ((u >> 3) << 2);   // 0..255
  const int h = local >> 5;
  const int q0 = (local & 31) * 128;

  // Q fragments in registers
  bf16x8 Qf[16];
  {
    const short* qp = qkv + ((long)(b * 4096 + q0 + w * 32 + lq)) * 2560 + h * 256;
    #pragma unroll
    for (int ds = 0; ds < 16; ++ds) Qf[ds] = ld_frag(qp + ds * 16 + hi * 8);
  }

  // staging pointers: 4 K-chunks + 4 V-chunks of 16B per thread per tile.
  // LDS dest LINEAR (gl_lds16 requirement); swizzle applied on global src (rule #21).
  const short* kptr[4];
  const short* vptr[4];
  #pragma unroll
  for (int p = 0; p < 4; ++p) {
    int c = p * 256 + t;
    int r = c >> 5, s = c & 31;                 // K tile row (kv), 16B slot in 512B row
    kptr[p] = qkv + ((long)(b * 4096 + r)) * 2560 + 2048 + ((s ^ (r & 7)) * 8);
  }
  #pragma unroll
  for (int p = 0; p < 4; ++p) {
    int c = p * 256 + t;
    int d = c >> 2, s = c & 3;                  // V^T tile row (d), 16B slot in 64B row
    vptr[p] = vtg + ((long)(b * 256 + d)) * 4096 + ((s ^ ((d >> 1) & 3)) * 8);
  }

#define STAGE(BUF) do {                                                          \
    _Pragma("unroll")                                                            \
    for (int p = 0; p < 4; ++p)                                                  \
      gl_lds16(kptr[p], KtS + (BUF) * 8192 + (p * 256 + t) * 8);                 \
    _Pragma("unroll")                                                            \
    for (int p = 0; p < 4; ++p)                                                  \
      gl_lds16(vptr[p], VtS + (BUF) * 8192 + (p * 256 + t) * 8);                 \
    _Pragma("unroll")                                                            \
    for (int p = 0; p < 4; ++p) { kptr[p] += 32 * 2560; vptr[p] += 32; }         \
  } while (0)

  STAGE(0);
  __syncthreads();

  f32x16 Oa[8] = {};
  float mrun = -3.0e38f, lrun = 0.0f;
  const int xk8 = (lq & 7) * 8;          // K read-side swizzle (shorts)
  const int xv8 = ((lq >> 1) & 3) * 8;   // V read-side swizzle (shorts)
  const int lv32 = lq * 32;
  int cur = 0;

  for (int kv0 = 0; kv0 < 4096; kv0 += 32) {
    if (kv0 + 32 < 4096) STAGE(cur ^ 1);    // prefetch next tile; hides under compute
    const short* Kc = KtS + cur * 8192;
    const short* Vc = VtS + cur * 8192;

    // St = K @ Q^T (swapped: softmax state lane-local at col=q=lq)
    // Two independent 8-deep MFMA chains (halves dep-chain latency); no setprio.
    f32x16 S0 = {}, S1 = {};
    #pragma unroll
    for (int ds = 0; ds < 8; ++ds) {
      bf16x8 a0 = ld_frag(Kc + lq * 256 + ((ds * 16 + hi * 8) ^ xk8));
      bf16x8 a1 = ld_frag(Kc + lq * 256 + (((ds + 8) * 16 + hi * 8) ^ xk8));
      S0 = __builtin_amdgcn_mfma_f32_32x32x16_bf16(a0, Qf[ds], S0, 0, 0, 0);
      S1 = __builtin_amdgcn_mfma_f32_32x32x16_bf16(a1, Qf[ds + 8], S1, 0, 0, 0);
    }
    f32x16 S;
    #pragma unroll
    for (int r = 0; r < 16; ++r) S[r] = S0[r] + S1[r];

    float smax = S[0];
    #pragma unroll
    for (int r = 1; r < 16; ++r) smax = fmaxf(smax, S[r]);
    smax = fmaxf(smax, __shfl_xor(smax, 32));

    // T13 defer-max: rescale only when max grew past threshold (rare)
    if (__any(smax > mrun + 8.0f)) {
      float mnew = fmaxf(mrun, smax);
      float alpha = __expf(mrun - mnew);
      #pragma unroll
      for (int r = 0; r < 16; ++r) {
        int qp2 = (r & 3) + 8 * (r >> 2) + 4 * hi;
        float ar = __shfl(alpha, qp2);
        #pragma unroll
        for (int df = 0; df < 8; ++df) Oa[df][r] *= ar;
      }
      lrun *= alpha;
      mrun = mnew;
    }
    float psum = 0.0f;
    #pragma unroll
    for (int r = 0; r < 16; ++r) { S[r] = __expf(S[r] - mrun); psum += S[r]; }
    psum += __shfl_xor(psum, 32);
    lrun += psum;

    // T12: P -> bf16 A-fragments fully in-register (cvt_pk + permlane32_swap)
    bf16x8 pa[2];
    #pragma unroll
    for (int kvs = 0; kvs < 2; ++kvs) {
      uint32_t x0, x1, y0, y1;
      asm("v_cvt_pk_bf16_f32 %0, %1, %2" : "=v"(x0) : "v"(S[8 * kvs + 0]), "v"(S[8 * kvs + 1]));
      asm("v_cvt_pk_bf16_f32 %0, %1, %2" : "=v"(x1) : "v"(S[8 * kvs + 2]), "v"(S[8 * kvs + 3]));
      asm("v_cvt_pk_bf16_f32 %0, %1, %2" : "=v"(y0) : "v"(S[8 * kvs + 4]), "v"(S[8 * kvs + 5]));
      asm("v_cvt_pk_bf16_f32 %0, %1, %2" : "=v"(y1) : "v"(S[8 * kvs + 6]), "v"(S[8 * kvs + 7]));
      asm("v_permlane32_swap_b32 %0, %1" : "+v"(x0), "+v"(y0));
      asm("v_permlane32_swap_b32 %0, %1" : "+v"(x1), "+v"(y1));
      i32x4 wv = { (int)x0, (int)x1, (int)y0, (int)y1 };
      pa[kvs] = __builtin_bit_cast(bf16x8, wv);
    }

    // PV: Oa += P @ V  (8 independent accumulator chains already)
    #pragma unroll
    for (int df = 0; df < 8; ++df)
      #pragma unroll
      for (int kvs = 0; kvs < 2; ++kvs) {
        bf16x8 vb = ld_frag(Vc + df * 1024 + lv32 + ((kvs * 16 + hi * 8) ^ xv8));
        Oa[df] = __builtin_amdgcn_mfma_f32_32x32x16_bf16(pa[kvs], vb, Oa[df], 0, 0, 0);
      }

    __syncthreads();   // stage(t+1) landed (vmcnt drain) + all reads of cur done
    cur ^= 1;
  }
#undef STAGE

  float linv = 1.0f / lrun;
  float lir[16];
  #pragma unroll
  for (int r = 0; r < 16; ++r) {
    int qp2 = (r & 3) + 8 * (r >> 2) + 4 * hi;
    lir[r] = __shfl(linv, qp2);
  }
  short* ob = og + ((long)(b * 4096 + q0)) * 2048 + h * 256;
  short* chunk = KtS;   // reuse 32KB: [128 q][128 d]
  #pragma unroll
  for (int half = 0; half < 2; ++half) {
    __syncthreads();
    #pragma unroll
    for (int df4 = 0; df4 < 4; ++df4) {
      #pragma unroll
      for (int r = 0; r < 16; ++r) {
        int qp2 = (r & 3) + 8 * (r >> 2) + 4 * hi;
        chunk[(w * 32 + qp2) * 128 + df4 * 32 + lq] = bf_bits(Oa[half * 4 + df4][r] * lir[r]);
      }
    }
    __syncthreads();
    #pragma unroll
    for (int p = 0; p < 8; ++p) {
      int idx = p * 256 + t, row = idx >> 4, dg = idx & 15;
      i32x4 val = *reinterpret_cast<const i32x4*>(chunk + row * 128 + dg * 8);
      *reinterpret_cast<i32x4*>(ob + (long)row * 2048 + half * 128 + dg * 8) = val;
    }
  }
}

// ---------------- launcher ----------------
extern "C" void kernel_launch(void* const* d_in, const int* in_sizes, int n_in,
                              void* d_out, int out_size, void* d_ws, size_t ws_size,
                              hipStream_t stream) {
  const float* x  = (const float*)d_in[0];
  const float* qw = (const float*)d_in[1];
  const float* kw = (const float*)d_in[2];
  const float* vw = (const float*)d_in[3];
  const float* ow = (const float*)d_in[4];
  float* out = (float*)d_out;
  char* ws = (char*)d_ws;

  short* xb  = (short*)(ws);                // [8192][2048] x bf16; reused as attn out
  short* wb  = (short*)(ws + 33554432);     // [2560][2048] fused qkv weights
  short* qkv = (short*)(ws + 44040192);     // [8192][2560]
  short* vtb = (short*)(ws + 85983232);     // [2][256][4096]
  float* ct  = (float*)(ws + 90177536);     // [4096][128]
  float* st  = (float*)(ws + 92274688);
  short* wob = (short*)(ws + 94371840);     // [2048][2048]

  cvt_bf16<<<16384, 256, 0, stream>>>(x,  xb, 4194304);
  cvt_w<<<5120, 256, 0, stream>>>(qw, kw, vw, wb);
  cvt_bf16<<<4096, 256, 0, stream>>>(ow, wob, 1048576);
  rope_table<<<2048, 256, 0, stream>>>(ct, st);

  // fused QKV projection: [8192][2048] @ [2560][2048]^T -> [8192][2560]
  gemm_bt<false><<<dim3(64, 20), 256, 0, stream>>>(xb, wb, qkv, 2048, 2560);

  rope_fused<<<9216, 256, 0, stream>>>(qkv, ct, st);   // q (1/sqrt(D) folded) + k
  transpose_v<<<1024, 256, 0, stream>>>(qkv, vtb);

  attn<<<512, 256, 0, stream>>>(qkv, vtb, xb);

  gemm_bt<true><<<dim3(64, 16), 256, 0, stream>>>(xb, wob, out, 2048, 2048);
}

// Round 11
// 650.526 us; speedup vs baseline: 1.0694x; 1.0694x over previous
//
#include <hip/hip_runtime.h>
#include <cstdint>

typedef __bf16 bf16x8 __attribute__((ext_vector_type(8)));
typedef float f32x4 __attribute__((ext_vector_type(4)));
typedef float f32x16 __attribute__((ext_vector_type(16)));
typedef short s16x4 __attribute__((ext_vector_type(4)));
typedef int i32x4 __attribute__((ext_vector_type(4)));

static __device__ __forceinline__ short bf_bits(float f) {
  uint32_t u = __builtin_bit_cast(uint32_t, f);
  u += 0x7fffu + ((u >> 16) & 1u);
  return (short)(u >> 16);
}
static __device__ __forceinline__ float bf_f(short s) {
  uint32_t u = ((uint32_t)(uint16_t)s) << 16;
  return __builtin_bit_cast(float, u);
}
static __device__ __forceinline__ bf16x8 ld_frag(const short* p) {
  i32x4 v = *reinterpret_cast<const i32x4*>(p);
  return __builtin_bit_cast(bf16x8, v);
}

typedef __attribute__((address_space(3))) uint32_t lds_u32_t;
typedef const __attribute__((address_space(1))) uint32_t glb_u32_t;
static __device__ __forceinline__ void gl_lds16(const void* g, const void* l) {
  __builtin_amdgcn_global_load_lds((glb_u32_t*)g,
                                   (lds_u32_t*)(uint32_t)(uintptr_t)l,
                                   16, 0, 0);
}

// ---------------- f32 -> bf16 convert ----------------
__global__ void cvt_bf16(const float* __restrict__ in, short* __restrict__ out, int n4) {
  int i = blockIdx.x * blockDim.x + threadIdx.x;
  if (i >= n4) return;
  float4 v = reinterpret_cast<const float4*>(in)[i];
  s16x4 o = { bf_bits(v.x), bf_bits(v.y), bf_bits(v.z), bf_bits(v.w) };
  reinterpret_cast<s16x4*>(out)[i] = o;
}

// ---------------- fused q/k/v weight convert into contiguous wb ----------------
__global__ void cvt_w(const float* __restrict__ qw, const float* __restrict__ kw,
                      const float* __restrict__ vw, short* __restrict__ out) {
  int i = blockIdx.x * blockDim.x + threadIdx.x;   // 1310720 float4s
  const float* src;
  int off;
  if (i < 1048576)      { src = qw; off = i; }
  else if (i < 1179648) { src = kw; off = i - 1048576; }
  else                  { src = vw; off = i - 1179648; }
  float4 v = reinterpret_cast<const float4*>(src)[off];
  s16x4 o = { bf_bits(v.x), bf_bits(v.y), bf_bits(v.z), bf_bits(v.w) };
  reinterpret_cast<s16x4*>(out)[i] = o;
}

// ---------------- RoPE tables: cos/sin [4096][128] f32 ----------------
__global__ void rope_table(float* __restrict__ ct, float* __restrict__ st) {
  int i = blockIdx.x * 256 + threadIdx.x;   // 524288
  int l = i >> 7, d = i & 127;
  float inv = expf(-0.07195578415625f * (float)d);   // ln(10000)/128
  float f = (float)l * inv;
  ct[i] = cosf(f);
  st[i] = sinf(f);
}

// ---------------- in-place RoPE on bf16 in fused qkv [8192][2560] ----------------
static __device__ __forceinline__ void rope_body(short* buf, const float* ct,
                                                 const float* st, int i, int cbase,
                                                 int hbits, float scale) {
  int dg = i & 31;
  int h = (i >> 5) & ((1 << hbits) - 1);
  int tok = i >> (5 + hbits);
  int l = tok & 4095;
  long base = (long)tok * 2560 + cbase + h * 256;
  int d = dg * 4;
  s16x4 x1 = *reinterpret_cast<const s16x4*>(buf + base + d);
  s16x4 x2 = *reinterpret_cast<const s16x4*>(buf + base + d + 128);
  float4 c = *reinterpret_cast<const float4*>(ct + l * 128 + d);
  float4 s = *reinterpret_cast<const float4*>(st + l * 128 + d);
  s16x4 o1, o2;
  o1.x = bf_bits((bf_f(x1.x) * c.x - bf_f(x2.x) * s.x) * scale);
  o1.y = bf_bits((bf_f(x1.y) * c.y - bf_f(x2.y) * s.y) * scale);
  o1.z = bf_bits((bf_f(x1.z) * c.z - bf_f(x2.z) * s.z) * scale);
  o1.w = bf_bits((bf_f(x1.w) * c.w - bf_f(x2.w) * s.w) * scale);
  o2.x = bf_bits((bf_f(x2.x) * c.x + bf_f(x1.x) * s.x) * scale);
  o2.y = bf_bits((bf_f(x2.y) * c.y + bf_f(x1.y) * s.y) * scale);
  o2.z = bf_bits((bf_f(x2.z) * c.z + bf_f(x1.z) * s.z) * scale);
  o2.w = bf_bits((bf_f(x2.w) * c.w + bf_f(x1.w) * s.w) * scale);
  *reinterpret_cast<s16x4*>(buf + base + d) = o1;
  *reinterpret_cast<s16x4*>(buf + base + d + 128) = o2;
}

// fused q-rope (i < 2097152, hbits=3, scale=1/16) + k-rope (hbits=0, col 2048)
__global__ void rope_fused(short* __restrict__ buf, const float* __restrict__ ct,
                           const float* __restrict__ st) {
  int j = blockIdx.x * blockDim.x + threadIdx.x;   // 2359296
  if (j < 2097152) rope_body(buf, ct, st, j, 0, 3, 0.0625f);
  else             rope_body(buf, ct, st, j - 2097152, 2048, 0, 1.0f);
}

// ---------------- V transpose: qkv cols 2304.. -> vt [2][256][4096] ----------------
__global__ void transpose_v(const short* __restrict__ qkv, short* __restrict__ vt) {
  int i = blockIdx.x * 256 + threadIdx.x;   // [b][lg 512][d 256], d fastest
  int d = i & 255;
  int lg = (i >> 8) & 511;
  int b = i >> 17;
  const short* src = qkv + ((long)b * 4096 + lg * 8) * 2560 + 2304 + d;
  short tmp[8];
  #pragma unroll
  for (int j = 0; j < 8; ++j) tmp[j] = src[(long)j * 2560];
  short* dst = vt + ((long)b * 256 + d) * 4096 + lg * 8;
  s16x4 lo = { tmp[0], tmp[1], tmp[2], tmp[3] };
  s16x4 hi4 = { tmp[4], tmp[5], tmp[6], tmp[7] };
  *reinterpret_cast<s16x4*>(dst) = lo;
  *reinterpret_cast<s16x4*>(dst + 4) = hi4;
}

// ---------------- GEMM: C[M,N] = A[M,K] @ B[N,K]^T, bf16, m97 structure ----------------
template <bool OUT_F32>
__global__ __launch_bounds__(256) void gemm_bt(const short* __restrict__ A,
                                               const short* __restrict__ B,
                                               void* __restrict__ C,
                                               int K, int ldc) {
  __shared__ short As[128 * 32];
  __shared__ short Bs[128 * 32];
  const int t = threadIdx.x;
  const int lane = t & 63;
  const int w = t >> 6;
  const long m0 = (long)blockIdx.x * 128;
  const long n0 = (long)blockIdx.y * 128;
  const int wr = (w >> 1) * 64, wc = (w & 1) * 64;
  const int fr = lane & 15, fk = (lane >> 4) * 8;
  f32x4 acc[4][4] = {};

  for (int k0 = 0; k0 < K; k0 += 32) {
    #pragma unroll
    for (int p = 0; p < 2; ++p) {
      int idx = p * 256 + t;
      gl_lds16(A + (m0 + (idx >> 2)) * K + k0 + (idx & 3) * 8, As + idx * 8);
    }
    #pragma unroll
    for (int p = 0; p < 2; ++p) {
      int idx = p * 256 + t;
      gl_lds16(B + (n0 + (idx >> 2)) * K + k0 + (idx & 3) * 8, Bs + idx * 8);
    }
    __syncthreads();
    bf16x8 af[4], bfr[4];
    #pragma unroll
    for (int i = 0; i < 4; ++i) af[i] = ld_frag(As + (wr + i * 16 + fr) * 32 + fk);
    #pragma unroll
    for (int j = 0; j < 4; ++j) bfr[j] = ld_frag(Bs + (wc + j * 16 + fr) * 32 + fk);
    #pragma unroll
    for (int i = 0; i < 4; ++i)
      #pragma unroll
      for (int j = 0; j < 4; ++j)
        acc[i][j] = __builtin_amdgcn_mfma_f32_16x16x32_bf16(af[i], bfr[j], acc[i][j], 0, 0, 0);
    __syncthreads();
  }
  const int er = lane >> 4, ec = lane & 15;
  #pragma unroll
  for (int i = 0; i < 4; ++i)
    #pragma unroll
    for (int j = 0; j < 4; ++j) {
      long col = n0 + wc + j * 16 + ec;
      #pragma unroll
      for (int r = 0; r < 4; ++r) {
        long row = m0 + wr + i * 16 + er * 4 + r;
        if constexpr (OUT_F32)
          reinterpret_cast<float*>(C)[row * ldc + col] = acc[i][j][r];
        else
          reinterpret_cast<short*>(C)[row * ldc + col] = bf_bits(acc[i][j][r]);
      }
    }
}

// ---------------- Flash attention (r2-proven structure, verbatim) ----------------
// qkv [8192][2560] bf16 (q pre-scaled by 1/16, roped; k roped at col 2048)
// vt  [2][256][4096] bf16 ;  out -> og [8192][2048] bf16
__global__ __launch_bounds__(256, 2) void attn(const short* __restrict__ qkv,
                                               const short* __restrict__ vtg,
                                               short* __restrict__ og) {
  __shared__ __align__(16) short KtS[2 * 32 * 256];   // 2 x 16KB, XOR-swizzled 512B rows
  __shared__ __align__(16) short VtS[2 * 256 * 32];   // 2 x 16KB, XOR-swizzled 64B rows
  const int t = threadIdx.x;
  const int lane = t & 63, w = t >> 6;
  const int lq = lane & 31, hi = lane >> 5;
  // XCD swizzle: batch b -> XCD half so each XCD's 4MB L2 holds one batch's K+V^T
  const int u = blockIdx.x;
  const int b = (u >> 2) & 1;
  const int local = (u & 3) | ((u >> 3) << 2);   // 0..255
  const int h = local >> 5;
  const int q0 = (local & 31) * 128;

  // Q fragments in registers
  bf16x8 Qf[16];
  {
    const short* qp = qkv + ((long)(b * 4096 + q0 + w * 32 + lq)) * 2560 + h * 256;
    #pragma unroll
    for (int ds = 0; ds < 16; ++ds) Qf[ds] = ld_frag(qp + ds * 16 + hi * 8);
  }

  // staging pointers: 4 K-chunks + 4 V-chunks of 16B per thread per tile.
  // LDS dest LINEAR (gl_lds16 requirement); swizzle applied on global src (rule #21).
  const short* kptr[4];
  const short* vptr[4];
  #pragma unroll
  for (int p = 0; p < 4; ++p) {
    int c = p * 256 + t;
    int r = c >> 5, s = c & 31;                 // K tile row (kv), 16B slot in 512B row
    kptr[p] = qkv + ((long)(b * 4096 + r)) * 2560 + 2048 + ((s ^ (r & 7)) * 8);
  }
  #pragma unroll
  for (int p = 0; p < 4; ++p) {
    int c = p * 256 + t;
    int d = c >> 2, s = c & 3;                  // V^T tile row (d), 16B slot in 64B row
    vptr[p] = vtg + ((long)(b * 256 + d)) * 4096 + ((s ^ ((d >> 1) & 3)) * 8);
  }

#define STAGE(BUF) do {                                                          \
    _Pragma("unroll")                                                            \
    for (int p = 0; p < 4; ++p)                                                  \
      gl_lds16(kptr[p], KtS + (BUF) * 8192 + (p * 256 + t) * 8);                 \
    _Pragma("unroll")                                                            \
    for (int p = 0; p < 4; ++p)                                                  \
      gl_lds16(vptr[p], VtS + (BUF) * 8192 + (p * 256 + t) * 8);                 \
    _Pragma("unroll")                                                            \
    for (int p = 0; p < 4; ++p) { kptr[p] += 32 * 2560; vptr[p] += 32; }         \
  } while (0)

  STAGE(0);
  __syncthreads();

  f32x16 Oa[8] = {};
  float mrun = -3.0e38f, lrun = 0.0f;
  const int xk8 = (lq & 7) * 8;          // K read-side swizzle (shorts)
  const int xv8 = ((lq >> 1) & 3) * 8;   // V read-side swizzle (shorts)
  const int lv32 = lq * 32;
  int cur = 0;

  for (int kv0 = 0; kv0 < 4096; kv0 += 32) {
    if (kv0 + 32 < 4096) STAGE(cur ^ 1);    // prefetch next tile; hides under compute
    const short* Kc = KtS + cur * 8192;
    const short* Vc = VtS + cur * 8192;

    // St = K @ Q^T (swapped: softmax state lane-local at col=q=lq)
    f32x16 S = {};
    #pragma unroll
    for (int ds = 0; ds < 16; ++ds) {
      bf16x8 a = ld_frag(Kc + lq * 256 + ((ds * 16 + hi * 8) ^ xk8));
      S = __builtin_amdgcn_mfma_f32_32x32x16_bf16(a, Qf[ds], S, 0, 0, 0);
    }
    float smax = S[0];
    #pragma unroll
    for (int r = 1; r < 16; ++r) smax = fmaxf(smax, S[r]);
    smax = fmaxf(smax, __shfl_xor(smax, 32));

    // T13 defer-max: rescale only when max grew past threshold (rare)
    if (__any(smax > mrun + 8.0f)) {
      float mnew = fmaxf(mrun, smax);
      float alpha = __expf(mrun - mnew);
      #pragma unroll
      for (int r = 0; r < 16; ++r) {
        int qp2 = (r & 3) + 8 * (r >> 2) + 4 * hi;
        float ar = __shfl(alpha, qp2);
        #pragma unroll
        for (int df = 0; df < 8; ++df) Oa[df][r] *= ar;
      }
      lrun *= alpha;
      mrun = mnew;
    }
    float psum = 0.0f;
    #pragma unroll
    for (int r = 0; r < 16; ++r) { S[r] = __expf(S[r] - mrun); psum += S[r]; }
    psum += __shfl_xor(psum, 32);
    lrun += psum;

    // T12: P -> bf16 A-fragments fully in-register (cvt_pk + permlane32_swap)
    bf16x8 pa[2];
    #pragma unroll
    for (int kvs = 0; kvs < 2; ++kvs) {
      uint32_t x0, x1, y0, y1;
      asm("v_cvt_pk_bf16_f32 %0, %1, %2" : "=v"(x0) : "v"(S[8 * kvs + 0]), "v"(S[8 * kvs + 1]));
      asm("v_cvt_pk_bf16_f32 %0, %1, %2" : "=v"(x1) : "v"(S[8 * kvs + 2]), "v"(S[8 * kvs + 3]));
      asm("v_cvt_pk_bf16_f32 %0, %1, %2" : "=v"(y0) : "v"(S[8 * kvs + 4]), "v"(S[8 * kvs + 5]));
      asm("v_cvt_pk_bf16_f32 %0, %1, %2" : "=v"(y1) : "v"(S[8 * kvs + 6]), "v"(S[8 * kvs + 7]));
      asm("v_permlane32_swap_b32 %0, %1" : "+v"(x0), "+v"(y0));
      asm("v_permlane32_swap_b32 %0, %1" : "+v"(x1), "+v"(y1));
      i32x4 wv = { (int)x0, (int)x1, (int)y0, (int)y1 };
      pa[kvs] = __builtin_bit_cast(bf16x8, wv);
    }

    // PV: Oa += P @ V
    #pragma unroll
    for (int df = 0; df < 8; ++df)
      #pragma unroll
      for (int kvs = 0; kvs < 2; ++kvs) {
        bf16x8 vb = ld_frag(Vc + df * 1024 + lv32 + ((kvs * 16 + hi * 8) ^ xv8));
        Oa[df] = __builtin_amdgcn_mfma_f32_32x32x16_bf16(pa[kvs], vb, Oa[df], 0, 0, 0);
      }

    __syncthreads();   // stage(t+1) landed (vmcnt drain) + all reads of cur done
    cur ^= 1;
  }
#undef STAGE

  float linv = 1.0f / lrun;
  float lir[16];
  #pragma unroll
  for (int r = 0; r < 16; ++r) {
    int qp2 = (r & 3) + 8 * (r >> 2) + 4 * hi;
    lir[r] = __shfl(linv, qp2);
  }
  short* ob = og + ((long)(b * 4096 + q0)) * 2048 + h * 256;
  short* chunk = KtS;   // reuse 32KB: [128 q][128 d]
  #pragma unroll
  for (int half = 0; half < 2; ++half) {
    __syncthreads();
    #pragma unroll
    for (int df4 = 0; df4 < 4; ++df4) {
      #pragma unroll
      for (int r = 0; r < 16; ++r) {
        int qp2 = (r & 3) + 8 * (r >> 2) + 4 * hi;
        chunk[(w * 32 + qp2) * 128 + df4 * 32 + lq] = bf_bits(Oa[half * 4 + df4][r] * lir[r]);
      }
    }
    __syncthreads();
    #pragma unroll
    for (int p = 0; p < 8; ++p) {
      int idx = p * 256 + t, row = idx >> 4, dg = idx & 15;
      i32x4 val = *reinterpret_cast<const i32x4*>(chunk + row * 128 + dg * 8);
      *reinterpret_cast<i32x4*>(ob + (long)row * 2048 + half * 128 + dg * 8) = val;
    }
  }
}

// ---------------- launcher ----------------
extern "C" void kernel_launch(void* const* d_in, const int* in_sizes, int n_in,
                              void* d_out, int out_size, void* d_ws, size_t ws_size,
                              hipStream_t stream) {
  const float* x  = (const float*)d_in[0];
  const float* qw = (const float*)d_in[1];
  const float* kw = (const float*)d_in[2];
  const float* vw = (const float*)d_in[3];
  const float* ow = (const float*)d_in[4];
  float* out = (float*)d_out;
  char* ws = (char*)d_ws;

  short* xb  = (short*)(ws);                // [8192][2048] x bf16; reused as attn out
  short* wb  = (short*)(ws + 33554432);     // [2560][2048] fused qkv weights
  short* qkv = (short*)(ws + 44040192);     // [8192][2560]
  short* vtb = (short*)(ws + 85983232);     // [2][256][4096]
  float* ct  = (float*)(ws + 90177536);     // [4096][128]
  float* st  = (float*)(ws + 92274688);
  short* wob = (short*)(ws + 94371840);     // [2048][2048]

  cvt_bf16<<<16384, 256, 0, stream>>>(x,  xb, 4194304);
  cvt_w<<<5120, 256, 0, stream>>>(qw, kw, vw, wb);
  cvt_bf16<<<4096, 256, 0, stream>>>(ow, wob, 1048576);
  rope_table<<<2048, 256, 0, stream>>>(ct, st);

  // fused QKV projection: [8192][2048] @ [2560][2048]^T -> [8192][2560]
  gemm_bt<false><<<dim3(64, 20), 256, 0, stream>>>(xb, wb, qkv, 2048, 2560);

  rope_fused<<<9216, 256, 0, stream>>>(qkv, ct, st);   // q (1/sqrt(D) folded) + k
  transpose_v<<<1024, 256, 0, stream>>>(qkv, vtb);

  attn<<<512, 256, 0, stream>>>(qkv, vtb, xb);

  gemm_bt<true><<<dim3(64, 16), 256, 0, stream>>>(xb, wob, out, 2048, 2048);
}

// Round 12
// 618.615 us; speedup vs baseline: 1.1245x; 1.0516x over previous
//
#include <hip/hip_runtime.h>
#include <cstdint>

typedef __bf16 bf16x8 __attribute__((ext_vector_type(8)));
typedef float f32x4 __attribute__((ext_vector_type(4)));
typedef float f32x16 __attribute__((ext_vector_type(16)));
typedef short s16x4 __attribute__((ext_vector_type(4)));
typedef int i32x4 __attribute__((ext_vector_type(4)));

static __device__ __forceinline__ short bf_bits(float f) {
  uint32_t u = __builtin_bit_cast(uint32_t, f);
  u += 0x7fffu + ((u >> 16) & 1u);
  return (short)(u >> 16);
}
static __device__ __forceinline__ float bf_f(short s) {
  uint32_t u = ((uint32_t)(uint16_t)s) << 16;
  return __builtin_bit_cast(float, u);
}
static __device__ __forceinline__ bf16x8 ld_frag(const short* p) {
  i32x4 v = *reinterpret_cast<const i32x4*>(p);
  return __builtin_bit_cast(bf16x8, v);
}

// Cross-half (lane ^ 32) reductions via permlane32_swap on VALU pipe.
// swap(a,b): a' = {a_lo||b_lo}, b' = {a_hi||b_hi} (semantics verified against the
// working T12 fragment-conversion block). With a,b distinct registers both holding
// v, every lane ends with {v[i&31], v[(i&31)+32]} -> op gives the cross-half
// reduction, bit-identical to __shfl_xor(v,32)-based form. The opaque v_mov forces
// distinct physical registers (r5's failure: compiler coalesced two same-valued
// "+v" operands into ONE register, degenerating the swap).
static __device__ __forceinline__ float xhalf_max(float v) {
  float a = v, b;
  asm("v_mov_b32 %0, %1" : "=v"(b) : "v"(v));
  asm("v_permlane32_swap_b32 %0, %1" : "+v"(a), "+v"(b));
  return fmaxf(a, b);
}
static __device__ __forceinline__ float xhalf_sum(float v) {
  float a = v, b;
  asm("v_mov_b32 %0, %1" : "=v"(b) : "v"(v));
  asm("v_permlane32_swap_b32 %0, %1" : "+v"(a), "+v"(b));
  return a + b;
}

typedef __attribute__((address_space(3))) uint32_t lds_u32_t;
typedef const __attribute__((address_space(1))) uint32_t glb_u32_t;
static __device__ __forceinline__ void gl_lds16(const void* g, const void* l) {
  __builtin_amdgcn_global_load_lds((glb_u32_t*)g,
                                   (lds_u32_t*)(uint32_t)(uintptr_t)l,
                                   16, 0, 0);
}

// ---------------- f32 -> bf16 convert ----------------
__global__ void cvt_bf16(const float* __restrict__ in, short* __restrict__ out, int n4) {
  int i = blockIdx.x * blockDim.x + threadIdx.x;
  if (i >= n4) return;
  float4 v = reinterpret_cast<const float4*>(in)[i];
  s16x4 o = { bf_bits(v.x), bf_bits(v.y), bf_bits(v.z), bf_bits(v.w) };
  reinterpret_cast<s16x4*>(out)[i] = o;
}

// ---------------- fused q/k/v weight convert into contiguous wb ----------------
__global__ void cvt_w(const float* __restrict__ qw, const float* __restrict__ kw,
                      const float* __restrict__ vw, short* __restrict__ out) {
  int i = blockIdx.x * blockDim.x + threadIdx.x;   // 1310720 float4s
  const float* src;
  int off;
  if (i < 1048576)      { src = qw; off = i; }
  else if (i < 1179648) { src = kw; off = i - 1048576; }
  else                  { src = vw; off = i - 1179648; }
  float4 v = reinterpret_cast<const float4*>(src)[off];
  s16x4 o = { bf_bits(v.x), bf_bits(v.y), bf_bits(v.z), bf_bits(v.w) };
  reinterpret_cast<s16x4*>(out)[i] = o;
}

// ---------------- RoPE tables: cos/sin [4096][128] f32 ----------------
__global__ void rope_table(float* __restrict__ ct, float* __restrict__ st) {
  int i = blockIdx.x * 256 + threadIdx.x;   // 524288
  int l = i >> 7, d = i & 127;
  float inv = expf(-0.07195578415625f * (float)d);   // ln(10000)/128
  float f = (float)l * inv;
  ct[i] = cosf(f);
  st[i] = sinf(f);
}

// ---------------- in-place RoPE on bf16 in fused qkv [8192][2560] ----------------
static __device__ __forceinline__ void rope_body(short* buf, const float* ct,
                                                 const float* st, int i, int cbase,
                                                 int hbits, float scale) {
  int dg = i & 31;
  int h = (i >> 5) & ((1 << hbits) - 1);
  int tok = i >> (5 + hbits);
  int l = tok & 4095;
  long base = (long)tok * 2560 + cbase + h * 256;
  int d = dg * 4;
  s16x4 x1 = *reinterpret_cast<const s16x4*>(buf + base + d);
  s16x4 x2 = *reinterpret_cast<const s16x4*>(buf + base + d + 128);
  float4 c = *reinterpret_cast<const float4*>(ct + l * 128 + d);
  float4 s = *reinterpret_cast<const float4*>(st + l * 128 + d);
  s16x4 o1, o2;
  o1.x = bf_bits((bf_f(x1.x) * c.x - bf_f(x2.x) * s.x) * scale);
  o1.y = bf_bits((bf_f(x1.y) * c.y - bf_f(x2.y) * s.y) * scale);
  o1.z = bf_bits((bf_f(x1.z) * c.z - bf_f(x2.z) * s.z) * scale);
  o1.w = bf_bits((bf_f(x1.w) * c.w - bf_f(x2.w) * s.w) * scale);
  o2.x = bf_bits((bf_f(x2.x) * c.x + bf_f(x1.x) * s.x) * scale);
  o2.y = bf_bits((bf_f(x2.y) * c.y + bf_f(x1.y) * s.y) * scale);
  o2.z = bf_bits((bf_f(x2.z) * c.z + bf_f(x1.z) * s.z) * scale);
  o2.w = bf_bits((bf_f(x2.w) * c.w + bf_f(x1.w) * s.w) * scale);
  *reinterpret_cast<s16x4*>(buf + base + d) = o1;
  *reinterpret_cast<s16x4*>(buf + base + d + 128) = o2;
}

// fused q-rope (i < 2097152, hbits=3, scale=1/16) + k-rope (hbits=0, col 2048)
__global__ void rope_fused(short* __restrict__ buf, const float* __restrict__ ct,
                           const float* __restrict__ st) {
  int j = blockIdx.x * blockDim.x + threadIdx.x;   // 2359296
  if (j < 2097152) rope_body(buf, ct, st, j, 0, 3, 0.0625f);
  else             rope_body(buf, ct, st, j - 2097152, 2048, 0, 1.0f);
}

// ---------------- V transpose: qkv cols 2304.. -> vt [2][256][4096] ----------------
__global__ void transpose_v(const short* __restrict__ qkv, short* __restrict__ vt) {
  int i = blockIdx.x * 256 + threadIdx.x;   // [b][lg 512][d 256], d fastest
  int d = i & 255;
  int lg = (i >> 8) & 511;
  int b = i >> 17;
  const short* src = qkv + ((long)b * 4096 + lg * 8) * 2560 + 2304 + d;
  short tmp[8];
  #pragma unroll
  for (int j = 0; j < 8; ++j) tmp[j] = src[(long)j * 2560];
  short* dst = vt + ((long)b * 256 + d) * 4096 + lg * 8;
  s16x4 lo = { tmp[0], tmp[1], tmp[2], tmp[3] };
  s16x4 hi4 = { tmp[4], tmp[5], tmp[6], tmp[7] };
  *reinterpret_cast<s16x4*>(dst) = lo;
  *reinterpret_cast<s16x4*>(dst + 4) = hi4;
}

// ---------------- GEMM: C[M,N] = A[M,K] @ B[N,K]^T, bf16, m97 structure ----------------
template <bool OUT_F32>
__global__ __launch_bounds__(256) void gemm_bt(const short* __restrict__ A,
                                               const short* __restrict__ B,
                                               void* __restrict__ C,
                                               int K, int ldc) {
  __shared__ short As[128 * 32];
  __shared__ short Bs[128 * 32];
  const int t = threadIdx.x;
  const int lane = t & 63;
  const int w = t >> 6;
  const long m0 = (long)blockIdx.x * 128;
  const long n0 = (long)blockIdx.y * 128;
  const int wr = (w >> 1) * 64, wc = (w & 1) * 64;
  const int fr = lane & 15, fk = (lane >> 4) * 8;
  f32x4 acc[4][4] = {};

  for (int k0 = 0; k0 < K; k0 += 32) {
    #pragma unroll
    for (int p = 0; p < 2; ++p) {
      int idx = p * 256 + t;
      gl_lds16(A + (m0 + (idx >> 2)) * K + k0 + (idx & 3) * 8, As + idx * 8);
    }
    #pragma unroll
    for (int p = 0; p < 2; ++p) {
      int idx = p * 256 + t;
      gl_lds16(B + (n0 + (idx >> 2)) * K + k0 + (idx & 3) * 8, Bs + idx * 8);
    }
    __syncthreads();
    bf16x8 af[4], bfr[4];
    #pragma unroll
    for (int i = 0; i < 4; ++i) af[i] = ld_frag(As + (wr + i * 16 + fr) * 32 + fk);
    #pragma unroll
    for (int j = 0; j < 4; ++j) bfr[j] = ld_frag(Bs + (wc + j * 16 + fr) * 32 + fk);
    #pragma unroll
    for (int i = 0; i < 4; ++i)
      #pragma unroll
      for (int j = 0; j < 4; ++j)
        acc[i][j] = __builtin_amdgcn_mfma_f32_16x16x32_bf16(af[i], bfr[j], acc[i][j], 0, 0, 0);
    __syncthreads();
  }
  const int er = lane >> 4, ec = lane & 15;
  #pragma unroll
  for (int i = 0; i < 4; ++i)
    #pragma unroll
    for (int j = 0; j < 4; ++j) {
      long col = n0 + wc + j * 16 + ec;
      #pragma unroll
      for (int r = 0; r < 4; ++r) {
        long row = m0 + wr + i * 16 + er * 4 + r;
        if constexpr (OUT_F32)
          reinterpret_cast<float*>(C)[row * ldc + col] = acc[i][j][r];
        else
          reinterpret_cast<short*>(C)[row * ldc + col] = bf_bits(acc[i][j][r]);
      }
    }
}

// ---------------- Flash attention (r2 structure; ONLY change: permlane cross-half) ----------------
// qkv [8192][2560] bf16 (q pre-scaled by 1/16, roped; k roped at col 2048)
// vt  [2][256][4096] bf16 ;  out -> og [8192][2048] bf16
__global__ __launch_bounds__(256, 2) void attn(const short* __restrict__ qkv,
                                               const short* __restrict__ vtg,
                                               short* __restrict__ og) {
  __shared__ __align__(16) short KtS[2 * 32 * 256];   // 2 x 16KB, XOR-swizzled 512B rows
  __shared__ __align__(16) short VtS[2 * 256 * 32];   // 2 x 16KB, XOR-swizzled 64B rows
  const int t = threadIdx.x;
  const int lane = t & 63, w = t >> 6;
  const int lq = lane & 31, hi = lane >> 5;
  // XCD swizzle: batch b -> XCD half so each XCD's 4MB L2 holds one batch's K+V^T
  const int u = blockIdx.x;
  const int b = (u >> 2) & 1;
  const int local = (u & 3) | ((u >> 3) << 2);   // 0..255
  const int h = local >> 5;
  const int q0 = (local & 31) * 128;

  // Q fragments in registers
  bf16x8 Qf[16];
  {
    const short* qp = qkv + ((long)(b * 4096 + q0 + w * 32 + lq)) * 2560 + h * 256;
    #pragma unroll
    for (int ds = 0; ds < 16; ++ds) Qf[ds] = ld_frag(qp + ds * 16 + hi * 8);
  }

  // staging pointers: 4 K-chunks + 4 V-chunks of 16B per thread per tile.
  // LDS dest LINEAR (gl_lds16 requirement); swizzle applied on global src (rule #21).
  const short* kptr[4];
  const short* vptr[4];
  #pragma unroll
  for (int p = 0; p < 4; ++p) {
    int c = p * 256 + t;
    int r = c >> 5, s = c & 31;                 // K tile row (kv), 16B slot in 512B row
    kptr[p] = qkv + ((long)(b * 4096 + r)) * 2560 + 2048 + ((s ^ (r & 7)) * 8);
  }
  #pragma unroll
  for (int p = 0; p < 4; ++p) {
    int c = p * 256 + t;
    int d = c >> 2, s = c & 3;                  // V^T tile row (d), 16B slot in 64B row
    vptr[p] = vtg + ((long)(b * 256 + d)) * 4096 + ((s ^ ((d >> 1) & 3)) * 8);
  }

#define STAGE(BUF) do {                                                          \
    _Pragma("unroll")                                                            \
    for (int p = 0; p < 4; ++p)                                                  \
      gl_lds16(kptr[p], KtS + (BUF) * 8192 + (p * 256 + t) * 8);                 \
    _Pragma("unroll")                                                            \
    for (int p = 0; p < 4; ++p)                                                  \
      gl_lds16(vptr[p], VtS + (BUF) * 8192 + (p * 256 + t) * 8);                 \
    _Pragma("unroll")                                                            \
    for (int p = 0; p < 4; ++p) { kptr[p] += 32 * 2560; vptr[p] += 32; }         \
  } while (0)

  STAGE(0);
  __syncthreads();

  f32x16 Oa[8] = {};
  float mrun = -3.0e38f, lrun = 0.0f;
  const int xk8 = (lq & 7) * 8;          // K read-side swizzle (shorts)
  const int xv8 = ((lq >> 1) & 3) * 8;   // V read-side swizzle (shorts)
  const int lv32 = lq * 32;
  int cur = 0;

  for (int kv0 = 0; kv0 < 4096; kv0 += 32) {
    if (kv0 + 32 < 4096) STAGE(cur ^ 1);    // prefetch next tile; hides under compute
    const short* Kc = KtS + cur * 8192;
    const short* Vc = VtS + cur * 8192;

    // St = K @ Q^T (swapped: softmax state lane-local at col=q=lq)
    f32x16 S = {};
    #pragma unroll
    for (int ds = 0; ds < 16; ++ds) {
      bf16x8 a = ld_frag(Kc + lq * 256 + ((ds * 16 + hi * 8) ^ xk8));
      S = __builtin_amdgcn_mfma_f32_32x32x16_bf16(a, Qf[ds], S, 0, 0, 0);
    }
    float smax = S[0];
    #pragma unroll
    for (int r = 1; r < 16; ++r) smax = fmaxf(smax, S[r]);
    smax = xhalf_max(smax);   // VALU permlane instead of ds_bpermute __shfl_xor

    // T13 defer-max: rescale only when max grew past threshold (rare)
    if (__any(smax > mrun + 8.0f)) {
      float mnew = fmaxf(mrun, smax);
      float alpha = __expf(mrun - mnew);
      #pragma unroll
      for (int r = 0; r < 16; ++r) {
        int qp2 = (r & 3) + 8 * (r >> 2) + 4 * hi;
        float ar = __shfl(alpha, qp2);
        #pragma unroll
        for (int df = 0; df < 8; ++df) Oa[df][r] *= ar;
      }
      lrun *= alpha;
      mrun = mnew;
    }
    float psum = 0.0f;
    #pragma unroll
    for (int r = 0; r < 16; ++r) { S[r] = __expf(S[r] - mrun); psum += S[r]; }
    lrun += xhalf_sum(psum);   // VALU permlane instead of ds_bpermute __shfl_xor

    // T12: P -> bf16 A-fragments fully in-register (cvt_pk + permlane32_swap)
    bf16x8 pa[2];
    #pragma unroll
    for (int kvs = 0; kvs < 2; ++kvs) {
      uint32_t x0, x1, y0, y1;
      asm("v_cvt_pk_bf16_f32 %0, %1, %2" : "=v"(x0) : "v"(S[8 * kvs + 0]), "v"(S[8 * kvs + 1]));
      asm("v_cvt_pk_bf16_f32 %0, %1, %2" : "=v"(x1) : "v"(S[8 * kvs + 2]), "v"(S[8 * kvs + 3]));
      asm("v_cvt_pk_bf16_f32 %0, %1, %2" : "=v"(y0) : "v"(S[8 * kvs + 4]), "v"(S[8 * kvs + 5]));
      asm("v_cvt_pk_bf16_f32 %0, %1, %2" : "=v"(y1) : "v"(S[8 * kvs + 6]), "v"(S[8 * kvs + 7]));
      asm("v_permlane32_swap_b32 %0, %1" : "+v"(x0), "+v"(y0));
      asm("v_permlane32_swap_b32 %0, %1" : "+v"(x1), "+v"(y1));
      i32x4 wv = { (int)x0, (int)x1, (int)y0, (int)y1 };
      pa[kvs] = __builtin_bit_cast(bf16x8, wv);
    }

    // PV: Oa += P @ V
    #pragma unroll
    for (int df = 0; df < 8; ++df)
      #pragma unroll
      for (int kvs = 0; kvs < 2; ++kvs) {
        bf16x8 vb = ld_frag(Vc + df * 1024 + lv32 + ((kvs * 16 + hi * 8) ^ xv8));
        Oa[df] = __builtin_amdgcn_mfma_f32_32x32x16_bf16(pa[kvs], vb, Oa[df], 0, 0, 0);
      }

    __syncthreads();   // stage(t+1) landed (vmcnt drain) + all reads of cur done
    cur ^= 1;
  }
#undef STAGE

  float linv = 1.0f / lrun;
  float lir[16];
  #pragma unroll
  for (int r = 0; r < 16; ++r) {
    int qp2 = (r & 3) + 8 * (r >> 2) + 4 * hi;
    lir[r] = __shfl(linv, qp2);
  }
  short* ob = og + ((long)(b * 4096 + q0)) * 2048 + h * 256;
  short* chunk = KtS;   // reuse 32KB: [128 q][128 d]
  #pragma unroll
  for (int half = 0; half < 2; ++half) {
    __syncthreads();
    #pragma unroll
    for (int df4 = 0; df4 < 4; ++df4) {
      #pragma unroll
      for (int r = 0; r < 16; ++r) {
        int qp2 = (r & 3) + 8 * (r >> 2) + 4 * hi;
        chunk[(w * 32 + qp2) * 128 + df4 * 32 + lq] = bf_bits(Oa[half * 4 + df4][r] * lir[r]);
      }
    }
    __syncthreads();
    #pragma unroll
    for (int p = 0; p < 8; ++p) {
      int idx = p * 256 + t, row = idx >> 4, dg = idx & 15;
      i32x4 val = *reinterpret_cast<const i32x4*>(chunk + row * 128 + dg * 8);
      *reinterpret_cast<i32x4*>(ob + (long)row * 2048 + half * 128 + dg * 8) = val;
    }
  }
}

// ---------------- launcher ----------------
extern "C" void kernel_launch(void* const* d_in, const int* in_sizes, int n_in,
                              void* d_out, int out_size, void* d_ws, size_t ws_size,
                              hipStream_t stream) {
  const float* x  = (const float*)d_in[0];
  const float* qw = (const float*)d_in[1];
  const float* kw = (const float*)d_in[2];
  const float* vw = (const float*)d_in[3];
  const float* ow = (const float*)d_in[4];
  float* out = (float*)d_out;
  char* ws = (char*)d_ws;

  short* xb  = (short*)(ws);                // [8192][2048] x bf16; reused as attn out
  short* wb  = (short*)(ws + 33554432);     // [2560][2048] fused qkv weights
  short* qkv = (short*)(ws + 44040192);     // [8192][2560]
  short* vtb = (short*)(ws + 85983232);     // [2][256][4096]
  float* ct  = (float*)(ws + 90177536);     // [4096][128]
  float* st  = (float*)(ws + 92274688);
  short* wob = (short*)(ws + 94371840);     // [2048][2048]

  cvt_bf16<<<16384, 256, 0, stream>>>(x,  xb, 4194304);
  cvt_w<<<5120, 256, 0, stream>>>(qw, kw, vw, wb);
  cvt_bf16<<<4096, 256, 0, stream>>>(ow, wob, 1048576);
  rope_table<<<2048, 256, 0, stream>>>(ct, st);

  // fused QKV projection: [8192][2048] @ [2560][2048]^T -> [8192][2560]
  gemm_bt<false><<<dim3(64, 20), 256, 0, stream>>>(xb, wb, qkv, 2048, 2560);

  rope_fused<<<9216, 256, 0, stream>>>(qkv, ct, st);   // q (1/sqrt(D) folded) + k
  transpose_v<<<1024, 256, 0, stream>>>(qkv, vtb);

  attn<<<512, 256, 0, stream>>>(qkv, vtb, xb);

  gemm_bt<true><<<dim3(64, 16), 256, 0, stream>>>(xb, wob, out, 2048, 2048);
}

// Round 13
// 593.482 us; speedup vs baseline: 1.1722x; 1.0423x over previous
//
#include <hip/hip_runtime.h>
#include <cstdint>

typedef __bf16 bf16x8 __attribute__((ext_vector_type(8)));
typedef float f32x4 __attribute__((ext_vector_type(4)));
typedef float f32x16 __attribute__((ext_vector_type(16)));
typedef short s16x4 __attribute__((ext_vector_type(4)));
typedef int i32x4 __attribute__((ext_vector_type(4)));

static __device__ __forceinline__ short bf_bits(float f) {
  uint32_t u = __builtin_bit_cast(uint32_t, f);
  u += 0x7fffu + ((u >> 16) & 1u);
  return (short)(u >> 16);
}
static __device__ __forceinline__ float bf_f(short s) {
  uint32_t u = ((uint32_t)(uint16_t)s) << 16;
  return __builtin_bit_cast(float, u);
}
static __device__ __forceinline__ bf16x8 ld_frag(const short* p) {
  i32x4 v = *reinterpret_cast<const i32x4*>(p);
  return __builtin_bit_cast(bf16x8, v);
}

// Cross-half (lane ^ 32) reductions via permlane32_swap on VALU pipe.
// swap(a,b): a' = {a_lo||b_lo}, b' = {a_hi||b_hi}. With a,b DISTINCT registers both
// holding v, every lane ends with {v[i&31], v[(i&31)+32]} -> op gives the cross-half
// reduction, bit-identical to __shfl_xor(v,32). The opaque v_mov forces distinct
// physical registers (r5's failure: coalescing degenerated the swap).
static __device__ __forceinline__ float xhalf_max(float v) {
  float a = v, b;
  asm("v_mov_b32 %0, %1" : "=v"(b) : "v"(v));
  asm("v_permlane32_swap_b32 %0, %1" : "+v"(a), "+v"(b));
  return fmaxf(a, b);
}
static __device__ __forceinline__ float xhalf_sum(float v) {
  float a = v, b;
  asm("v_mov_b32 %0, %1" : "=v"(b) : "v"(v));
  asm("v_permlane32_swap_b32 %0, %1" : "+v"(a), "+v"(b));
  return a + b;
}

typedef __attribute__((address_space(3))) uint32_t lds_u32_t;
typedef const __attribute__((address_space(1))) uint32_t glb_u32_t;
static __device__ __forceinline__ void gl_lds16(const void* g, const void* l) {
  __builtin_amdgcn_global_load_lds((glb_u32_t*)g,
                                   (lds_u32_t*)(uint32_t)(uintptr_t)l,
                                   16, 0, 0);
}

// ---------------- f32 -> bf16 convert ----------------
__global__ void cvt_bf16(const float* __restrict__ in, short* __restrict__ out, int n4) {
  int i = blockIdx.x * blockDim.x + threadIdx.x;
  if (i >= n4) return;
  float4 v = reinterpret_cast<const float4*>(in)[i];
  s16x4 o = { bf_bits(v.x), bf_bits(v.y), bf_bits(v.z), bf_bits(v.w) };
  reinterpret_cast<s16x4*>(out)[i] = o;
}

// ---------------- fused q/k/v weight convert into contiguous wb ----------------
__global__ void cvt_w(const float* __restrict__ qw, const float* __restrict__ kw,
                      const float* __restrict__ vw, short* __restrict__ out) {
  int i = blockIdx.x * blockDim.x + threadIdx.x;   // 1310720 float4s
  const float* src;
  int off;
  if (i < 1048576)      { src = qw; off = i; }
  else if (i < 1179648) { src = kw; off = i - 1048576; }
  else                  { src = vw; off = i - 1179648; }
  float4 v = reinterpret_cast<const float4*>(src)[off];
  s16x4 o = { bf_bits(v.x), bf_bits(v.y), bf_bits(v.z), bf_bits(v.w) };
  reinterpret_cast<s16x4*>(out)[i] = o;
}

// ---------------- RoPE tables: cos/sin [4096][128] f32 ----------------
__global__ void rope_table(float* __restrict__ ct, float* __restrict__ st) {
  int i = blockIdx.x * 256 + threadIdx.x;   // 524288
  int l = i >> 7, d = i & 127;
  float inv = expf(-0.07195578415625f * (float)d);   // ln(10000)/128
  float f = (float)l * inv;
  ct[i] = cosf(f);
  st[i] = sinf(f);
}

// ---------------- in-place RoPE on bf16 in fused qkv [8192][2560] ----------------
static __device__ __forceinline__ void rope_body(short* buf, const float* ct,
                                                 const float* st, int i, int cbase,
                                                 int hbits, float scale) {
  int dg = i & 31;
  int h = (i >> 5) & ((1 << hbits) - 1);
  int tok = i >> (5 + hbits);
  int l = tok & 4095;
  long base = (long)tok * 2560 + cbase + h * 256;
  int d = dg * 4;
  s16x4 x1 = *reinterpret_cast<const s16x4*>(buf + base + d);
  s16x4 x2 = *reinterpret_cast<const s16x4*>(buf + base + d + 128);
  float4 c = *reinterpret_cast<const float4*>(ct + l * 128 + d);
  float4 s = *reinterpret_cast<const float4*>(st + l * 128 + d);
  s16x4 o1, o2;
  o1.x = bf_bits((bf_f(x1.x) * c.x - bf_f(x2.x) * s.x) * scale);
  o1.y = bf_bits((bf_f(x1.y) * c.y - bf_f(x2.y) * s.y) * scale);
  o1.z = bf_bits((bf_f(x1.z) * c.z - bf_f(x2.z) * s.z) * scale);
  o1.w = bf_bits((bf_f(x1.w) * c.w - bf_f(x2.w) * s.w) * scale);
  o2.x = bf_bits((bf_f(x2.x) * c.x + bf_f(x1.x) * s.x) * scale);
  o2.y = bf_bits((bf_f(x2.y) * c.y + bf_f(x1.y) * s.y) * scale);
  o2.z = bf_bits((bf_f(x2.z) * c.z + bf_f(x1.z) * s.z) * scale);
  o2.w = bf_bits((bf_f(x2.w) * c.w + bf_f(x1.w) * s.w) * scale);
  *reinterpret_cast<s16x4*>(buf + base + d) = o1;
  *reinterpret_cast<s16x4*>(buf + base + d + 128) = o2;
}

// fused q-rope (i < 2097152, hbits=3, scale=1/16) + k-rope (hbits=0, col 2048)
__global__ void rope_fused(short* __restrict__ buf, const float* __restrict__ ct,
                           const float* __restrict__ st) {
  int j = blockIdx.x * blockDim.x + threadIdx.x;   // 2359296
  if (j < 2097152) rope_body(buf, ct, st, j, 0, 3, 0.0625f);
  else             rope_body(buf, ct, st, j - 2097152, 2048, 0, 1.0f);
}

// ---------------- V transpose: qkv cols 2304.. -> vt [2][256][4096] ----------------
__global__ void transpose_v(const short* __restrict__ qkv, short* __restrict__ vt) {
  int i = blockIdx.x * 256 + threadIdx.x;   // [b][lg 512][d 256], d fastest
  int d = i & 255;
  int lg = (i >> 8) & 511;
  int b = i >> 17;
  const short* src = qkv + ((long)b * 4096 + lg * 8) * 2560 + 2304 + d;
  short tmp[8];
  #pragma unroll
  for (int j = 0; j < 8; ++j) tmp[j] = src[(long)j * 2560];
  short* dst = vt + ((long)b * 256 + d) * 4096 + lg * 8;
  s16x4 lo = { tmp[0], tmp[1], tmp[2], tmp[3] };
  s16x4 hi4 = { tmp[4], tmp[5], tmp[6], tmp[7] };
  *reinterpret_cast<s16x4*>(dst) = lo;
  *reinterpret_cast<s16x4*>(dst + 4) = hi4;
}

// ---------------- GEMM: C[M,N] = A[M,K] @ B[N,K]^T, bf16 ----------------
// m97 structure with BK=64 (half the barrier-drain events vs BK=32) and (r&7)
// 16B-chunk XOR swizzle: linear LDS dest (gl_lds16 req) + inverse-swizzled global
// src + XOR on read (rule #21; pattern proven in attn K-staging). Accumulation
// stays k-sequential per acc element -> bit-identical results.
template <bool OUT_F32>
__global__ __launch_bounds__(256) void gemm_bt(const short* __restrict__ A,
                                               const short* __restrict__ B,
                                               void* __restrict__ C,
                                               int K, int ldc) {
  __shared__ short As[128 * 64];
  __shared__ short Bs[128 * 64];
  const int t = threadIdx.x;
  const int lane = t & 63;
  const int w = t >> 6;
  const long m0 = (long)blockIdx.x * 128;
  const long n0 = (long)blockIdx.y * 128;
  const int wr = (w >> 1) * 64, wc = (w & 1) * 64;
  const int fr = lane & 15, fk = (lane >> 4) * 8;
  f32x4 acc[4][4] = {};

  for (int k0 = 0; k0 < K; k0 += 64) {
    // stage 128x64 tiles; row = idx>>3, 8-short group kg = idx&7.
    // LDS[row][c*8..] holds global kcol ((c ^ (row&7))*8): inverse-swizzled src.
    #pragma unroll
    for (int p = 0; p < 4; ++p) {
      int idx = p * 256 + t, row = idx >> 3, kg = idx & 7;
      gl_lds16(A + (m0 + row) * K + k0 + ((kg ^ (row & 7)) * 8), As + idx * 8);
    }
    #pragma unroll
    for (int p = 0; p < 4; ++p) {
      int idx = p * 256 + t, row = idx >> 3, kg = idx & 7;
      gl_lds16(B + (n0 + row) * K + k0 + ((kg ^ (row & 7)) * 8), Bs + idx * 8);
    }
    __syncthreads();
    #pragma unroll
    for (int ks = 0; ks < 2; ++ks) {
      bf16x8 af[4], bfr[4];
      #pragma unroll
      for (int i = 0; i < 4; ++i) {
        int r = wr + i * 16 + fr;
        af[i] = ld_frag(As + r * 64 + ((ks * 32 + fk) ^ ((r & 7) * 8)));
      }
      #pragma unroll
      for (int j = 0; j < 4; ++j) {
        int r = wc + j * 16 + fr;
        bfr[j] = ld_frag(Bs + r * 64 + ((ks * 32 + fk) ^ ((r & 7) * 8)));
      }
      #pragma unroll
      for (int i = 0; i < 4; ++i)
        #pragma unroll
        for (int j = 0; j < 4; ++j)
          acc[i][j] = __builtin_amdgcn_mfma_f32_16x16x32_bf16(af[i], bfr[j], acc[i][j], 0, 0, 0);
    }
    __syncthreads();
  }
  const int er = lane >> 4, ec = lane & 15;
  #pragma unroll
  for (int i = 0; i < 4; ++i)
    #pragma unroll
    for (int j = 0; j < 4; ++j) {
      long col = n0 + wc + j * 16 + ec;
      #pragma unroll
      for (int r = 0; r < 4; ++r) {
        long row = m0 + wr + i * 16 + er * 4 + r;
        if constexpr (OUT_F32)
          reinterpret_cast<float*>(C)[row * ldc + col] = acc[i][j][r];
        else
          reinterpret_cast<short*>(C)[row * ldc + col] = bf_bits(acc[i][j][r]);
      }
    }
}

// ---------------- Flash attention (r12-proven, byte-identical) ----------------
// qkv [8192][2560] bf16 (q pre-scaled by 1/16, roped; k roped at col 2048)
// vt  [2][256][4096] bf16 ;  out -> og [8192][2048] bf16
__global__ __launch_bounds__(256, 2) void attn(const short* __restrict__ qkv,
                                               const short* __restrict__ vtg,
                                               short* __restrict__ og) {
  __shared__ __align__(16) short KtS[2 * 32 * 256];   // 2 x 16KB, XOR-swizzled 512B rows
  __shared__ __align__(16) short VtS[2 * 256 * 32];   // 2 x 16KB, XOR-swizzled 64B rows
  const int t = threadIdx.x;
  const int lane = t & 63, w = t >> 6;
  const int lq = lane & 31, hi = lane >> 5;
  // XCD swizzle: batch b -> XCD half so each XCD's 4MB L2 holds one batch's K+V^T
  const int u = blockIdx.x;
  const int b = (u >> 2) & 1;
  const int local = (u & 3) | ((u >> 3) << 2);   // 0..255
  const int h = local >> 5;
  const int q0 = (local & 31) * 128;

  // Q fragments in registers
  bf16x8 Qf[16];
  {
    const short* qp = qkv + ((long)(b * 4096 + q0 + w * 32 + lq)) * 2560 + h * 256;
    #pragma unroll
    for (int ds = 0; ds < 16; ++ds) Qf[ds] = ld_frag(qp + ds * 16 + hi * 8);
  }

  // staging pointers: 4 K-chunks + 4 V-chunks of 16B per thread per tile.
  // LDS dest LINEAR (gl_lds16 requirement); swizzle applied on global src (rule #21).
  const short* kptr[4];
  const short* vptr[4];
  #pragma unroll
  for (int p = 0; p < 4; ++p) {
    int c = p * 256 + t;
    int r = c >> 5, s = c & 31;                 // K tile row (kv), 16B slot in 512B row
    kptr[p] = qkv + ((long)(b * 4096 + r)) * 2560 + 2048 + ((s ^ (r & 7)) * 8);
  }
  #pragma unroll
  for (int p = 0; p < 4; ++p) {
    int c = p * 256 + t;
    int d = c >> 2, s = c & 3;                  // V^T tile row (d), 16B slot in 64B row
    vptr[p] = vtg + ((long)(b * 256 + d)) * 4096 + ((s ^ ((d >> 1) & 3)) * 8);
  }

#define STAGE(BUF) do {                                                          \
    _Pragma("unroll")                                                            \
    for (int p = 0; p < 4; ++p)                                                  \
      gl_lds16(kptr[p], KtS + (BUF) * 8192 + (p * 256 + t) * 8);                 \
    _Pragma("unroll")                                                            \
    for (int p = 0; p < 4; ++p)                                                  \
      gl_lds16(vptr[p], VtS + (BUF) * 8192 + (p * 256 + t) * 8);                 \
    _Pragma("unroll")                                                            \
    for (int p = 0; p < 4; ++p) { kptr[p] += 32 * 2560; vptr[p] += 32; }         \
  } while (0)

  STAGE(0);
  __syncthreads();

  f32x16 Oa[8] = {};
  float mrun = -3.0e38f, lrun = 0.0f;
  const int xk8 = (lq & 7) * 8;          // K read-side swizzle (shorts)
  const int xv8 = ((lq >> 1) & 3) * 8;   // V read-side swizzle (shorts)
  const int lv32 = lq * 32;
  int cur = 0;

  for (int kv0 = 0; kv0 < 4096; kv0 += 32) {
    if (kv0 + 32 < 4096) STAGE(cur ^ 1);    // prefetch next tile; hides under compute
    const short* Kc = KtS + cur * 8192;
    const short* Vc = VtS + cur * 8192;

    // St = K @ Q^T (swapped: softmax state lane-local at col=q=lq)
    f32x16 S = {};
    #pragma unroll
    for (int ds = 0; ds < 16; ++ds) {
      bf16x8 a = ld_frag(Kc + lq * 256 + ((ds * 16 + hi * 8) ^ xk8));
      S = __builtin_amdgcn_mfma_f32_32x32x16_bf16(a, Qf[ds], S, 0, 0, 0);
    }
    float smax = S[0];
    #pragma unroll
    for (int r = 1; r < 16; ++r) smax = fmaxf(smax, S[r]);
    smax = xhalf_max(smax);   // VALU permlane instead of ds_bpermute __shfl_xor

    // T13 defer-max: rescale only when max grew past threshold (rare)
    if (__any(smax > mrun + 8.0f)) {
      float mnew = fmaxf(mrun, smax);
      float alpha = __expf(mrun - mnew);
      #pragma unroll
      for (int r = 0; r < 16; ++r) {
        int qp2 = (r & 3) + 8 * (r >> 2) + 4 * hi;
        float ar = __shfl(alpha, qp2);
        #pragma unroll
        for (int df = 0; df < 8; ++df) Oa[df][r] *= ar;
      }
      lrun *= alpha;
      mrun = mnew;
    }
    float psum = 0.0f;
    #pragma unroll
    for (int r = 0; r < 16; ++r) { S[r] = __expf(S[r] - mrun); psum += S[r]; }
    lrun += xhalf_sum(psum);   // VALU permlane instead of ds_bpermute __shfl_xor

    // T12: P -> bf16 A-fragments fully in-register (cvt_pk + permlane32_swap)
    bf16x8 pa[2];
    #pragma unroll
    for (int kvs = 0; kvs < 2; ++kvs) {
      uint32_t x0, x1, y0, y1;
      asm("v_cvt_pk_bf16_f32 %0, %1, %2" : "=v"(x0) : "v"(S[8 * kvs + 0]), "v"(S[8 * kvs + 1]));
      asm("v_cvt_pk_bf16_f32 %0, %1, %2" : "=v"(x1) : "v"(S[8 * kvs + 2]), "v"(S[8 * kvs + 3]));
      asm("v_cvt_pk_bf16_f32 %0, %1, %2" : "=v"(y0) : "v"(S[8 * kvs + 4]), "v"(S[8 * kvs + 5]));
      asm("v_cvt_pk_bf16_f32 %0, %1, %2" : "=v"(y1) : "v"(S[8 * kvs + 6]), "v"(S[8 * kvs + 7]));
      asm("v_permlane32_swap_b32 %0, %1" : "+v"(x0), "+v"(y0));
      asm("v_permlane32_swap_b32 %0, %1" : "+v"(x1), "+v"(y1));
      i32x4 wv = { (int)x0, (int)x1, (int)y0, (int)y1 };
      pa[kvs] = __builtin_bit_cast(bf16x8, wv);
    }

    // PV: Oa += P @ V
    #pragma unroll
    for (int df = 0; df < 8; ++df)
      #pragma unroll
      for (int kvs = 0; kvs < 2; ++kvs) {
        bf16x8 vb = ld_frag(Vc + df * 1024 + lv32 + ((kvs * 16 + hi * 8) ^ xv8));
        Oa[df] = __builtin_amdgcn_mfma_f32_32x32x16_bf16(pa[kvs], vb, Oa[df], 0, 0, 0);
      }

    __syncthreads();   // stage(t+1) landed (vmcnt drain) + all reads of cur done
    cur ^= 1;
  }
#undef STAGE

  float linv = 1.0f / lrun;
  float lir[16];
  #pragma unroll
  for (int r = 0; r < 16; ++r) {
    int qp2 = (r & 3) + 8 * (r >> 2) + 4 * hi;
    lir[r] = __shfl(linv, qp2);
  }
  short* ob = og + ((long)(b * 4096 + q0)) * 2048 + h * 256;
  short* chunk = KtS;   // reuse 32KB: [128 q][128 d]
  #pragma unroll
  for (int half = 0; half < 2; ++half) {
    __syncthreads();
    #pragma unroll
    for (int df4 = 0; df4 < 4; ++df4) {
      #pragma unroll
      for (int r = 0; r < 16; ++r) {
        int qp2 = (r & 3) + 8 * (r >> 2) + 4 * hi;
        chunk[(w * 32 + qp2) * 128 + df4 * 32 + lq] = bf_bits(Oa[half * 4 + df4][r] * lir[r]);
      }
    }
    __syncthreads();
    #pragma unroll
    for (int p = 0; p < 8; ++p) {
      int idx = p * 256 + t, row = idx >> 4, dg = idx & 15;
      i32x4 val = *reinterpret_cast<const i32x4*>(chunk + row * 128 + dg * 8);
      *reinterpret_cast<i32x4*>(ob + (long)row * 2048 + half * 128 + dg * 8) = val;
    }
  }
}

// ---------------- launcher ----------------
extern "C" void kernel_launch(void* const* d_in, const int* in_sizes, int n_in,
                              void* d_out, int out_size, void* d_ws, size_t ws_size,
                              hipStream_t stream) {
  const float* x  = (const float*)d_in[0];
  const float* qw = (const float*)d_in[1];
  const float* kw = (const float*)d_in[2];
  const float* vw = (const float*)d_in[3];
  const float* ow = (const float*)d_in[4];
  float* out = (float*)d_out;
  char* ws = (char*)d_ws;

  short* xb  = (short*)(ws);                // [8192][2048] x bf16; reused as attn out
  short* wb  = (short*)(ws + 33554432);     // [2560][2048] fused qkv weights
  short* qkv = (short*)(ws + 44040192);     // [8192][2560]
  short* vtb = (short*)(ws + 85983232);     // [2][256][4096]
  float* ct  = (float*)(ws + 90177536);     // [4096][128]
  float* st  = (float*)(ws + 92274688);
  short* wob = (short*)(ws + 94371840);     // [2048][2048]

  cvt_bf16<<<16384, 256, 0, stream>>>(x,  xb, 4194304);
  cvt_w<<<5120, 256, 0, stream>>>(qw, kw, vw, wb);
  cvt_bf16<<<4096, 256, 0, stream>>>(ow, wob, 1048576);
  rope_table<<<2048, 256, 0, stream>>>(ct, st);

  // fused QKV projection: [8192][2048] @ [2560][2048]^T -> [8192][2560]
  gemm_bt<false><<<dim3(64, 20), 256, 0, stream>>>(xb, wb, qkv, 2048, 2560);

  rope_fused<<<9216, 256, 0, stream>>>(qkv, ct, st);   // q (1/sqrt(D) folded) + k
  transpose_v<<<1024, 256, 0, stream>>>(qkv, vtb);

  attn<<<512, 256, 0, stream>>>(qkv, vtb, xb);

  gemm_bt<true><<<dim3(64, 16), 256, 0, stream>>>(xb, wob, out, 2048, 2048);
}

// Round 14
// 585.092 us; speedup vs baseline: 1.1890x; 1.0143x over previous
//
#include <hip/hip_runtime.h>
#include <cstdint>

typedef __bf16 bf16x8 __attribute__((ext_vector_type(8)));
typedef float f32x4 __attribute__((ext_vector_type(4)));
typedef float f32x16 __attribute__((ext_vector_type(16)));
typedef short s16x4 __attribute__((ext_vector_type(4)));
typedef int i32x4 __attribute__((ext_vector_type(4)));

static __device__ __forceinline__ short bf_bits(float f) {
  uint32_t u = __builtin_bit_cast(uint32_t, f);
  u += 0x7fffu + ((u >> 16) & 1u);
  return (short)(u >> 16);
}
static __device__ __forceinline__ float bf_f(short s) {
  uint32_t u = ((uint32_t)(uint16_t)s) << 16;
  return __builtin_bit_cast(float, u);
}
static __device__ __forceinline__ bf16x8 ld_frag(const short* p) {
  i32x4 v = *reinterpret_cast<const i32x4*>(p);
  return __builtin_bit_cast(bf16x8, v);
}

// Cross-half (lane ^ 32) reductions via permlane32_swap on VALU pipe.
// swap(a,b): a' = {a_lo||b_lo}, b' = {a_hi||b_hi}. With a,b DISTINCT registers both
// holding v, every lane ends with {v[i&31], v[(i&31)+32]} -> op gives the cross-half
// reduction, bit-identical to __shfl_xor(v,32). The opaque v_mov forces distinct
// physical registers (r5's failure: coalescing degenerated the swap).
static __device__ __forceinline__ float xhalf_max(float v) {
  float a = v, b;
  asm("v_mov_b32 %0, %1" : "=v"(b) : "v"(v));
  asm("v_permlane32_swap_b32 %0, %1" : "+v"(a), "+v"(b));
  return fmaxf(a, b);
}
static __device__ __forceinline__ float xhalf_sum(float v) {
  float a = v, b;
  asm("v_mov_b32 %0, %1" : "=v"(b) : "v"(v));
  asm("v_permlane32_swap_b32 %0, %1" : "+v"(a), "+v"(b));
  return a + b;
}

typedef __attribute__((address_space(3))) uint32_t lds_u32_t;
typedef const __attribute__((address_space(1))) uint32_t glb_u32_t;
static __device__ __forceinline__ void gl_lds16(const void* g, const void* l) {
  __builtin_amdgcn_global_load_lds((glb_u32_t*)g,
                                   (lds_u32_t*)(uint32_t)(uintptr_t)l,
                                   16, 0, 0);
}

// ---------------- fused prep: f32->bf16 converts (x, qkv-w, o-w) + RoPE tables ----------------
// Region-split grid; all boundaries 256-aligned so blocks are branch-uniform.
__global__ void prep(const float* __restrict__ x, const float* __restrict__ qw,
                     const float* __restrict__ kw, const float* __restrict__ vw,
                     const float* __restrict__ ow, short* __restrict__ xb,
                     short* __restrict__ wb, short* __restrict__ wob,
                     float* __restrict__ ct, float* __restrict__ st) {
  int i = blockIdx.x * blockDim.x + threadIdx.x;   // 6684672 total
  if (i < 6553600) {                               // convert regions (float4 units)
    const float* src; short* dst; int off;
    if (i < 4194304)      { src = x;  dst = xb;                off = i; }
    else if (i < 5242880) { src = qw; dst = wb;                off = i - 4194304; }
    else if (i < 5373952) { src = kw; dst = wb + 2048 * 2048;  off = i - 5242880; }
    else if (i < 5505024) { src = vw; dst = wb + 2304 * 2048;  off = i - 5373952; }
    else                  { src = ow; dst = wob;               off = i - 5505024; }
    float4 v = reinterpret_cast<const float4*>(src)[off];
    s16x4 o = { bf_bits(v.x), bf_bits(v.y), bf_bits(v.z), bf_bits(v.w) };
    reinterpret_cast<s16x4*>(dst)[off] = o;
  } else {                                         // RoPE tables, 4 entries/thread
    int j4 = (i - 6553600) << 2;                   // 0..524284, same formula as before
    int l = j4 >> 7, d0 = j4 & 127;
    float cv[4], sv[4];
    #pragma unroll
    for (int c = 0; c < 4; ++c) {
      float inv = expf(-0.07195578415625f * (float)(d0 + c));   // ln(10000)/128
      float f = (float)l * inv;
      cv[c] = cosf(f);
      sv[c] = sinf(f);
    }
    float4 c4 = { cv[0], cv[1], cv[2], cv[3] };
    float4 s4 = { sv[0], sv[1], sv[2], sv[3] };
    *reinterpret_cast<float4*>(ct + j4) = c4;
    *reinterpret_cast<float4*>(st + j4) = s4;
  }
}

// ---------------- in-place RoPE on bf16 in fused qkv [8192][2560] ----------------
static __device__ __forceinline__ void rope_body(short* buf, const float* ct,
                                                 const float* st, int i, int cbase,
                                                 int hbits, float scale) {
  int dg = i & 31;
  int h = (i >> 5) & ((1 << hbits) - 1);
  int tok = i >> (5 + hbits);
  int l = tok & 4095;
  long base = (long)tok * 2560 + cbase + h * 256;
  int d = dg * 4;
  s16x4 x1 = *reinterpret_cast<const s16x4*>(buf + base + d);
  s16x4 x2 = *reinterpret_cast<const s16x4*>(buf + base + d + 128);
  float4 c = *reinterpret_cast<const float4*>(ct + l * 128 + d);
  float4 s = *reinterpret_cast<const float4*>(st + l * 128 + d);
  s16x4 o1, o2;
  o1.x = bf_bits((bf_f(x1.x) * c.x - bf_f(x2.x) * s.x) * scale);
  o1.y = bf_bits((bf_f(x1.y) * c.y - bf_f(x2.y) * s.y) * scale);
  o1.z = bf_bits((bf_f(x1.z) * c.z - bf_f(x2.z) * s.z) * scale);
  o1.w = bf_bits((bf_f(x1.w) * c.w - bf_f(x2.w) * s.w) * scale);
  o2.x = bf_bits((bf_f(x2.x) * c.x + bf_f(x1.x) * s.x) * scale);
  o2.y = bf_bits((bf_f(x2.y) * c.y + bf_f(x1.y) * s.y) * scale);
  o2.z = bf_bits((bf_f(x2.z) * c.z + bf_f(x1.z) * s.z) * scale);
  o2.w = bf_bits((bf_f(x2.w) * c.w + bf_f(x1.w) * s.w) * scale);
  *reinterpret_cast<s16x4*>(buf + base + d) = o1;
  *reinterpret_cast<s16x4*>(buf + base + d + 128) = o2;
}

// ---------------- fused q-rope + k-rope + V transpose ----------------
// rope touches qkv cols 0..2303; transpose reads cols 2304.. -> disjoint, order-free.
__global__ void rope_tv(short* __restrict__ qkv, const float* __restrict__ ct,
                        const float* __restrict__ st, short* __restrict__ vt) {
  int j = blockIdx.x * blockDim.x + threadIdx.x;   // 2621440 total
  if (j < 2097152)      rope_body(qkv, ct, st, j, 0, 3, 0.0625f);        // q (1/16 folded)
  else if (j < 2359296) rope_body(qkv, ct, st, j - 2097152, 2048, 0, 1.0f); // k
  else {                                           // V transpose -> vt [2][256][4096]
    int i = j - 2359296;                           // 262144: [b][lg 512][d 256]
    int d = i & 255;
    int lg = (i >> 8) & 511;
    int b = i >> 17;
    const short* src = qkv + ((long)b * 4096 + lg * 8) * 2560 + 2304 + d;
    short tmp[8];
    #pragma unroll
    for (int jj = 0; jj < 8; ++jj) tmp[jj] = src[(long)jj * 2560];
    short* dst = vt + ((long)b * 256 + d) * 4096 + lg * 8;
    s16x4 lo = { tmp[0], tmp[1], tmp[2], tmp[3] };
    s16x4 hi4 = { tmp[4], tmp[5], tmp[6], tmp[7] };
    *reinterpret_cast<s16x4*>(dst) = lo;
    *reinterpret_cast<s16x4*>(dst + 4) = hi4;
  }
}

// ---------------- GEMM: C[M,N] = A[M,K] @ B[N,K]^T, bf16 ----------------
// m97 structure with BK=64 (half the barrier-drain events vs BK=32) and (r&7)
// 16B-chunk XOR swizzle: linear LDS dest (gl_lds16 req) + inverse-swizzled global
// src + XOR on read (rule #21). r13-proven (-8..12% vs BK=32).
template <bool OUT_F32>
__global__ __launch_bounds__(256) void gemm_bt(const short* __restrict__ A,
                                               const short* __restrict__ B,
                                               void* __restrict__ C,
                                               int K, int ldc) {
  __shared__ short As[128 * 64];
  __shared__ short Bs[128 * 64];
  const int t = threadIdx.x;
  const int lane = t & 63;
  const int w = t >> 6;
  const long m0 = (long)blockIdx.x * 128;
  const long n0 = (long)blockIdx.y * 128;
  const int wr = (w >> 1) * 64, wc = (w & 1) * 64;
  const int fr = lane & 15, fk = (lane >> 4) * 8;
  f32x4 acc[4][4] = {};

  for (int k0 = 0; k0 < K; k0 += 64) {
    #pragma unroll
    for (int p = 0; p < 4; ++p) {
      int idx = p * 256 + t, row = idx >> 3, kg = idx & 7;
      gl_lds16(A + (m0 + row) * K + k0 + ((kg ^ (row & 7)) * 8), As + idx * 8);
    }
    #pragma unroll
    for (int p = 0; p < 4; ++p) {
      int idx = p * 256 + t, row = idx >> 3, kg = idx & 7;
      gl_lds16(B + (n0 + row) * K + k0 + ((kg ^ (row & 7)) * 8), Bs + idx * 8);
    }
    __syncthreads();
    #pragma unroll
    for (int ks = 0; ks < 2; ++ks) {
      bf16x8 af[4], bfr[4];
      #pragma unroll
      for (int i = 0; i < 4; ++i) {
        int r = wr + i * 16 + fr;
        af[i] = ld_frag(As + r * 64 + ((ks * 32 + fk) ^ ((r & 7) * 8)));
      }
      #pragma unroll
      for (int j = 0; j < 4; ++j) {
        int r = wc + j * 16 + fr;
        bfr[j] = ld_frag(Bs + r * 64 + ((ks * 32 + fk) ^ ((r & 7) * 8)));
      }
      #pragma unroll
      for (int i = 0; i < 4; ++i)
        #pragma unroll
        for (int j = 0; j < 4; ++j)
          acc[i][j] = __builtin_amdgcn_mfma_f32_16x16x32_bf16(af[i], bfr[j], acc[i][j], 0, 0, 0);
    }
    __syncthreads();
  }
  const int er = lane >> 4, ec = lane & 15;
  #pragma unroll
  for (int i = 0; i < 4; ++i)
    #pragma unroll
    for (int j = 0; j < 4; ++j) {
      long col = n0 + wc + j * 16 + ec;
      #pragma unroll
      for (int r = 0; r < 4; ++r) {
        long row = m0 + wr + i * 16 + er * 4 + r;
        if constexpr (OUT_F32)
          reinterpret_cast<float*>(C)[row * ldc + col] = acc[i][j][r];
        else
          reinterpret_cast<short*>(C)[row * ldc + col] = bf_bits(acc[i][j][r]);
      }
    }
}

// ---------------- Flash attention (r12/r13-proven, byte-identical) ----------------
// qkv [8192][2560] bf16 (q pre-scaled by 1/16, roped; k roped at col 2048)
// vt  [2][256][4096] bf16 ;  out -> og [8192][2048] bf16
__global__ __launch_bounds__(256, 2) void attn(const short* __restrict__ qkv,
                                               const short* __restrict__ vtg,
                                               short* __restrict__ og) {
  __shared__ __align__(16) short KtS[2 * 32 * 256];   // 2 x 16KB, XOR-swizzled 512B rows
  __shared__ __align__(16) short VtS[2 * 256 * 32];   // 2 x 16KB, XOR-swizzled 64B rows
  const int t = threadIdx.x;
  const int lane = t & 63, w = t >> 6;
  const int lq = lane & 31, hi = lane >> 5;
  // XCD swizzle: batch b -> XCD half so each XCD's 4MB L2 holds one batch's K+V^T
  const int u = blockIdx.x;
  const int b = (u >> 2) & 1;
  const int local = (u & 3) | ((u >> 3) << 2);   // 0..255
  const int h = local >> 5;
  const int q0 = (local & 31) * 128;

  // Q fragments in registers
  bf16x8 Qf[16];
  {
    const short* qp = qkv + ((long)(b * 4096 + q0 + w * 32 + lq)) * 2560 + h * 256;
    #pragma unroll
    for (int ds = 0; ds < 16; ++ds) Qf[ds] = ld_frag(qp + ds * 16 + hi * 8);
  }

  // staging pointers: 4 K-chunks + 4 V-chunks of 16B per thread per tile.
  // LDS dest LINEAR (gl_lds16 requirement); swizzle applied on global src (rule #21).
  const short* kptr[4];
  const short* vptr[4];
  #pragma unroll
  for (int p = 0; p < 4; ++p) {
    int c = p * 256 + t;
    int r = c >> 5, s = c & 31;                 // K tile row (kv), 16B slot in 512B row
    kptr[p] = qkv + ((long)(b * 4096 + r)) * 2560 + 2048 + ((s ^ (r & 7)) * 8);
  }
  #pragma unroll
  for (int p = 0; p < 4; ++p) {
    int c = p * 256 + t;
    int d = c >> 2, s = c & 3;                  // V^T tile row (d), 16B slot in 64B row
    vptr[p] = vtg + ((long)(b * 256 + d)) * 4096 + ((s ^ ((d >> 1) & 3)) * 8);
  }

#define STAGE(BUF) do {                                                          \
    _Pragma("unroll")                                                            \
    for (int p = 0; p < 4; ++p)                                                  \
      gl_lds16(kptr[p], KtS + (BUF) * 8192 + (p * 256 + t) * 8);                 \
    _Pragma("unroll")                                                            \
    for (int p = 0; p < 4; ++p)                                                  \
      gl_lds16(vptr[p], VtS + (BUF) * 8192 + (p * 256 + t) * 8);                 \
    _Pragma("unroll")                                                            \
    for (int p = 0; p < 4; ++p) { kptr[p] += 32 * 2560; vptr[p] += 32; }         \
  } while (0)

  STAGE(0);
  __syncthreads();

  f32x16 Oa[8] = {};
  float mrun = -3.0e38f, lrun = 0.0f;
  const int xk8 = (lq & 7) * 8;          // K read-side swizzle (shorts)
  const int xv8 = ((lq >> 1) & 3) * 8;   // V read-side swizzle (shorts)
  const int lv32 = lq * 32;
  int cur = 0;

  for (int kv0 = 0; kv0 < 4096; kv0 += 32) {
    if (kv0 + 32 < 4096) STAGE(cur ^ 1);    // prefetch next tile; hides under compute
    const short* Kc = KtS + cur * 8192;
    const short* Vc = VtS + cur * 8192;

    // St = K @ Q^T (swapped: softmax state lane-local at col=q=lq)
    f32x16 S = {};
    #pragma unroll
    for (int ds = 0; ds < 16; ++ds) {
      bf16x8 a = ld_frag(Kc + lq * 256 + ((ds * 16 + hi * 8) ^ xk8));
      S = __builtin_amdgcn_mfma_f32_32x32x16_bf16(a, Qf[ds], S, 0, 0, 0);
    }
    float smax = S[0];
    #pragma unroll
    for (int r = 1; r < 16; ++r) smax = fmaxf(smax, S[r]);
    smax = xhalf_max(smax);   // VALU permlane instead of ds_bpermute __shfl_xor

    // T13 defer-max: rescale only when max grew past threshold (rare)
    if (__any(smax > mrun + 8.0f)) {
      float mnew = fmaxf(mrun, smax);
      float alpha = __expf(mrun - mnew);
      #pragma unroll
      for (int r = 0; r < 16; ++r) {
        int qp2 = (r & 3) + 8 * (r >> 2) + 4 * hi;
        float ar = __shfl(alpha, qp2);
        #pragma unroll
        for (int df = 0; df < 8; ++df) Oa[df][r] *= ar;
      }
      lrun *= alpha;
      mrun = mnew;
    }
    float psum = 0.0f;
    #pragma unroll
    for (int r = 0; r < 16; ++r) { S[r] = __expf(S[r] - mrun); psum += S[r]; }
    lrun += xhalf_sum(psum);   // VALU permlane instead of ds_bpermute __shfl_xor

    // T12: P -> bf16 A-fragments fully in-register (cvt_pk + permlane32_swap)
    bf16x8 pa[2];
    #pragma unroll
    for (int kvs = 0; kvs < 2; ++kvs) {
      uint32_t x0, x1, y0, y1;
      asm("v_cvt_pk_bf16_f32 %0, %1, %2" : "=v"(x0) : "v"(S[8 * kvs + 0]), "v"(S[8 * kvs + 1]));
      asm("v_cvt_pk_bf16_f32 %0, %1, %2" : "=v"(x1) : "v"(S[8 * kvs + 2]), "v"(S[8 * kvs + 3]));
      asm("v_cvt_pk_bf16_f32 %0, %1, %2" : "=v"(y0) : "v"(S[8 * kvs + 4]), "v"(S[8 * kvs + 5]));
      asm("v_cvt_pk_bf16_f32 %0, %1, %2" : "=v"(y1) : "v"(S[8 * kvs + 6]), "v"(S[8 * kvs + 7]));
      asm("v_permlane32_swap_b32 %0, %1" : "+v"(x0), "+v"(y0));
      asm("v_permlane32_swap_b32 %0, %1" : "+v"(x1), "+v"(y1));
      i32x4 wv = { (int)x0, (int)x1, (int)y0, (int)y1 };
      pa[kvs] = __builtin_bit_cast(bf16x8, wv);
    }

    // PV: Oa += P @ V
    #pragma unroll
    for (int df = 0; df < 8; ++df)
      #pragma unroll
      for (int kvs = 0; kvs < 2; ++kvs) {
        bf16x8 vb = ld_frag(Vc + df * 1024 + lv32 + ((kvs * 16 + hi * 8) ^ xv8));
        Oa[df] = __builtin_amdgcn_mfma_f32_32x32x16_bf16(pa[kvs], vb, Oa[df], 0, 0, 0);
      }

    __syncthreads();   // stage(t+1) landed (vmcnt drain) + all reads of cur done
    cur ^= 1;
  }
#undef STAGE

  float linv = 1.0f / lrun;
  float lir[16];
  #pragma unroll
  for (int r = 0; r < 16; ++r) {
    int qp2 = (r & 3) + 8 * (r >> 2) + 4 * hi;
    lir[r] = __shfl(linv, qp2);
  }
  short* ob = og + ((long)(b * 4096 + q0)) * 2048 + h * 256;
  short* chunk = KtS;   // reuse 32KB: [128 q][128 d]
  #pragma unroll
  for (int half = 0; half < 2; ++half) {
    __syncthreads();
    #pragma unroll
    for (int df4 = 0; df4 < 4; ++df4) {
      #pragma unroll
      for (int r = 0; r < 16; ++r) {
        int qp2 = (r & 3) + 8 * (r >> 2) + 4 * hi;
        chunk[(w * 32 + qp2) * 128 + df4 * 32 + lq] = bf_bits(Oa[half * 4 + df4][r] * lir[r]);
      }
    }
    __syncthreads();
    #pragma unroll
    for (int p = 0; p < 8; ++p) {
      int idx = p * 256 + t, row = idx >> 4, dg = idx & 15;
      i32x4 val = *reinterpret_cast<const i32x4*>(chunk + row * 128 + dg * 8);
      *reinterpret_cast<i32x4*>(ob + (long)row * 2048 + half * 128 + dg * 8) = val;
    }
  }
}

// ---------------- launcher (5 dispatches) ----------------
extern "C" void kernel_launch(void* const* d_in, const int* in_sizes, int n_in,
                              void* d_out, int out_size, void* d_ws, size_t ws_size,
                              hipStream_t stream) {
  const float* x  = (const float*)d_in[0];
  const float* qw = (const float*)d_in[1];
  const float* kw = (const float*)d_in[2];
  const float* vw = (const float*)d_in[3];
  const float* ow = (const float*)d_in[4];
  float* out = (float*)d_out;
  char* ws = (char*)d_ws;

  short* xb  = (short*)(ws);                // [8192][2048] x bf16; reused as attn out
  short* wb  = (short*)(ws + 33554432);     // [2560][2048] fused qkv weights
  short* qkv = (short*)(ws + 44040192);     // [8192][2560]
  short* vtb = (short*)(ws + 85983232);     // [2][256][4096]
  float* ct  = (float*)(ws + 90177536);     // [4096][128]
  float* st  = (float*)(ws + 92274688);
  short* wob = (short*)(ws + 94371840);     // [2048][2048]

  prep<<<26112, 256, 0, stream>>>(x, qw, kw, vw, ow, xb, wb, wob, ct, st);

  // fused QKV projection: [8192][2048] @ [2560][2048]^T -> [8192][2560]
  gemm_bt<false><<<dim3(64, 20), 256, 0, stream>>>(xb, wb, qkv, 2048, 2560);

  rope_tv<<<10240, 256, 0, stream>>>(qkv, ct, st, vtb);   // q-rope + k-rope + V^T

  attn<<<512, 256, 0, stream>>>(qkv, vtb, xb);

  gemm_bt<true><<<dim3(64, 16), 256, 0, stream>>>(xb, wob, out, 2048, 2048);
}